// Round 12
// baseline (2719.410 us; speedup 1.0000x reference)
//
#include <hip/hip_runtime.h>

typedef unsigned short u16;
typedef unsigned int u32;
typedef unsigned long long u64;
typedef __attribute__((ext_vector_type(8))) short bf16x8;
typedef __attribute__((ext_vector_type(4))) float f32x4;

#define DEV __device__ __forceinline__

DEV float bf2f(u16 u) { unsigned v = ((unsigned)u) << 16; float f; __builtin_memcpy(&f, &v, 4); return f; }
DEV u16 f2bf(float f) { unsigned u; __builtin_memcpy(&u, &f, 4); u += 0x7FFFu + ((u >> 16) & 1u); return (u16)(u >> 16); }
DEV float sigm(float x) { return 1.f / (1.f + __expf(-x)); }
DEV float tanha(float x) { x = fminf(9.f, fmaxf(-9.f, x)); float t = __expf(2.f * x); return (t - 1.f) / (t + 1.f); }

// async global->LDS, 16B per lane; LDS dest is wave-uniform base + lane*16 (linear).
// XOR-swizzle pre-applied to the GLOBAL source address (involution; m104/m173 rule).
DEV void gload16(const void* g, void* l) {
    __builtin_amdgcn_global_load_lds((const __attribute__((address_space(1))) unsigned*)g,
                                     (__attribute__((address_space(3))) unsigned*)l, 16, 0, 0);
}

// ---------------- converts / init ----------------
__global__ __launch_bounds__(256) void cvt_kernel(const float* __restrict__ s, u16* __restrict__ d, long long n) {
    long long i = ((long long)blockIdx.x * 256 + threadIdx.x) * 4;
    if (i < n) {
        float4 v = *(const float4*)(s + i);
        uint2 o;
        o.x = (unsigned)f2bf(v.x) | ((unsigned)f2bf(v.y) << 16);
        o.y = (unsigned)f2bf(v.z) | ((unsigned)f2bf(v.w) << 16);
        *(uint2*)(d + i) = o;
    }
}

__global__ __launch_bounds__(256) void cvt_wout_kernel(const float* __restrict__ s, u16* __restrict__ d) {
    long long i = ((long long)blockIdx.x * 256 + threadIdx.x) * 4;  // over 8192*1024
    int row = (int)(i >> 10), col = (int)(i & 1023);
    uint2 o;
    if (row < 8000) {
        float4 v = *(const float4*)(s + (size_t)row * 1024 + col);
        o.x = (unsigned)f2bf(v.x) | ((unsigned)f2bf(v.y) << 16);
        o.y = (unsigned)f2bf(v.z) | ((unsigned)f2bf(v.w) << 16);
    } else { o.x = 0u; o.y = 0u; }
    *(uint2*)(d + i) = o;
}

__global__ __launch_bounds__(256) void badd_kernel(const float* __restrict__ a, const float* __restrict__ b,
                                                   float* __restrict__ o, int n) {
    int i = blockIdx.x * 256 + threadIdx.x;
    if (i < n) o[i] = a[i] + b[i];
}

// h1ring layout: [slot(256)][jb(64)][b(64)][jc(16)]  (block-contiguous 2KB regions)
// h2ring layout: [slot(256)][jb2(128)][b(64)][jc(8)] (block-contiguous 1KB regions)
__global__ __launch_bounds__(256) void init_kernel(const float* __restrict__ h0, u16* __restrict__ h1ring,
                                                   u16* __restrict__ h2ring, u32* __restrict__ flg1,
                                                   u32* __restrict__ flg2) {
    int i = blockIdx.x * 256 + threadIdx.x;  // 65536 total
    if (i < 65536) {
        int b = i >> 10, col = i & 1023;
        h1ring[((col >> 4) << 10) + (b << 4) + (col & 15)] = f2bf(h0[i]);  // slot 0 = h0
        h2ring[i] = 0;                                                    // slot 0 = 0
    }
    if (i < 16384) flg1[i] = (i < 64) ? 1u : 0u;    // slot 0 ready
    if (i < 32768) flg2[i] = (i < 128) ? 1u : 0u;   // slot 0 ready
}

// ---------------- m97-shape 128x128 bf16 GEMM (C = A @ B^T + bias) ----------------
// 4 waves, each owns a 64x64 quadrant (4x4 16x16 fragments); BK=64; 32KB LDS;
// gload_lds w16 staging with source-side XOR swizzle. 1-D grid NPX*128 ordered
// {xl(8), y(128), xg}: each XCD keeps its 8 B-panels (8*256KB=2MB) L2-resident.
// M=128 = two t-groups (t=2y+h); reads clamp t<=254, stores guarded (t<255).
// MODE 0: phase A, K=512, A-row = emb[gt[b*256+t]]; out X1 gate-innermost.
// MODE 1: phase C, K=1024, A-row = H2 [t][k>>3][b][k&7]; out f32 logits (b*255+t rows).
template <int MODE, int K>
__global__ __launch_bounds__(256) void gemm_kernel(const u16* __restrict__ Asrc, const u16* __restrict__ Bmat,
                                                   const int* __restrict__ gt, const float* __restrict__ bias,
                                                   void* __restrict__ outp) {
    __shared__ uint4 AldsV[1024];  // 128 x 64 bf16 = 16 KiB
    __shared__ uint4 BldsV[1024];  // 128 x 64 bf16 = 16 KiB
    char* Al = (char*)AldsV;
    char* Bl = (char*)BldsV;
    const int bid = blockIdx.x;
    const int xl = bid & 7, y = (bid >> 3) & 127, xg = bid >> 10;
    const int bx = (xg << 3) + xl;
    const int n0 = bx << 7;
    const int tid = threadIdx.x;
    const int lane = tid & 63, wid = tid >> 6;
    const int wm = wid >> 1, wn = wid & 1;  // wave quadrant

    // hoisted per-chunk A-row metadata (4 A-chunks per thread)
    int tq[4], tok[4];
#pragma unroll
    for (int q = 0; q < 4; ++q) {
        int c = tid + (q << 8);
        int r = c >> 3;                  // 0..127
        int t = (y << 1) + (r >> 6);
        if (t > 254) t = 254;            // clamp (reads only; stores guarded)
        tq[q] = t;
        if (MODE == 0) tok[q] = gt[(r & 63) * 256 + t];
    }

    f32x4 acc[4][4] = {};

    for (int k0 = 0; k0 < K; k0 += 64) {
        // ---- stage A: 1024 chunks of 16B (linear dest, swizzled source) ----
#pragma unroll
        for (int q = 0; q < 4; ++q) {
            int c = tid + (q << 8);
            int row = c >> 3, kc = c & 7;
            int kcs = kc ^ (row & 7);
            const u16* src;
            if (MODE == 0) {
                src = Asrc + (size_t)tok[q] * 512 + k0 + (kcs << 3);
            } else {
                src = Asrc + ((size_t)tq[q] << 16) + ((size_t)((k0 >> 3) + kcs) << 9) + ((row & 63) << 3);
            }
            gload16(src, Al + (q << 12) + (wid << 10));
        }
        // ---- stage B: 1024 chunks ----
#pragma unroll
        for (int q = 0; q < 4; ++q) {
            int c = tid + (q << 8);
            int row = c >> 3, kc = c & 7;
            int kcs = kc ^ (row & 7);
            gload16(Bmat + (size_t)(n0 + row) * K + k0 + (kcs << 3), Bl + (q << 12) + (wid << 10));
        }
        asm volatile("s_waitcnt vmcnt(0)" ::: "memory");
        __syncthreads();
#pragma unroll
        for (int kb2 = 0; kb2 < 2; ++kb2) {
            int kc = (kb2 << 2) + (lane >> 4);
            bf16x8 af[4], bf[4];
#pragma unroll
            for (int mt = 0; mt < 4; ++mt) {
                int row = (wm << 6) + (mt << 4) + (lane & 15);
                af[mt] = *(const bf16x8*)(Al + row * 128 + ((kc ^ (row & 7)) << 4));
            }
#pragma unroll
            for (int nt = 0; nt < 4; ++nt) {
                int row = (wn << 6) + (nt << 4) + (lane & 15);
                bf[nt] = *(const bf16x8*)(Bl + row * 128 + ((kc ^ (row & 7)) << 4));
            }
#pragma unroll
            for (int mt = 0; mt < 4; ++mt)
#pragma unroll
                for (int nt = 0; nt < 4; ++nt)
                    acc[mt][nt] = __builtin_amdgcn_mfma_f32_16x16x32_bf16(af[mt], bf[nt], acc[mt][nt], 0, 0, 0);
        }
        __syncthreads();
    }

    // epilogue (C/D layout: col = lane&15, row = (lane>>4)*4 + r)
#pragma unroll
    for (int nt = 0; nt < 4; ++nt) {
        int n = n0 + (wn << 6) + (nt << 4) + (lane & 15);
        float bv = 0.f;
        if (MODE == 0) bv = bias[n];
        else if (n < 8000) bv = bias[n];
#pragma unroll
        for (int mt = 0; mt < 4; ++mt) {
#pragma unroll
            for (int r = 0; r < 4; ++r) {
                int ml = (wm << 6) + (mt << 4) + ((lane >> 4) << 2) + r;
                int t = (y << 1) + (ml >> 6);
                int b = ml & 63;
                float v = acc[mt][nt][r] + bv;
                if (t < 255) {
                    if (MODE == 0) {
                        ((u16*)outp)[((size_t)((t << 6) + b) << 12) + ((n & 1023) << 2) + (n >> 10)] = f2bf(v);
                    } else {
                        if (n < 8000) ((float*)outp)[(size_t)(b * 255 + t) * 8000 + n] = v;
                    }
                }
            }
        }
    }
}

// ---------------- persistent dataflow 2-layer LSTM (flag-based, split L2 loop) ----
// blocks 0..63:  layer1, j0=bid*16.  blocks 64..191: layer2, j0=(bid-64)*8.
// Publish: sc1 data stores -> vmcnt(0) -> __syncthreads -> ONE flag store/block.
// L2 loop split: {poll flg1[s+1] -> h1 read + Wih2-half MFMA} BEFORE the serial
// {poll flg2[s] -> h2 read + Whh2-half MFMA -> act -> publish}. H2 mirror store
// issues AFTER the flag (off the critical path; consumed only post-kernel).
__global__ __launch_bounds__(256, 1) void lstm_kernel(const u16* __restrict__ X1, const float* __restrict__ c0,
                                                      u16* __restrict__ h1ring, u16* __restrict__ h2ring,
                                                      u16* __restrict__ H2, const u16* __restrict__ Whh1,
                                                      const u16* __restrict__ Wih2, const u16* __restrict__ Whh2,
                                                      const float* __restrict__ b2, u32* __restrict__ flg1,
                                                      u32* __restrict__ flg2) {
    __shared__ uint4 WldsV[8192];  // 128 KiB weight slice
    __shared__ u64 scr[256];       // repack scratch (wave-private regions)
    char* Wb = (char*)WldsV;
    u16* scr16 = (u16*)scr;
    const int tid = threadIdx.x;
    const int lane = tid & 63, wid = tid >> 6;
    const int bid = blockIdx.x;
    const bool isL1 = (bid < 64);
    const int j0 = isL1 ? (bid << 4) : ((bid - 64) << 3);

    // ---- stage weights into LDS (XOR-swizzled rows) ----
    if (isL1) {
#pragma unroll 8
        for (int q = 0; q < 32; ++q) {
            int c = tid + (q << 8);
            int row = c >> 7, kc = c & 127;
            int gcol = ((row >> 4) << 10) + j0 + (row & 15);
            uint4 v = *(const uint4*)(Whh1 + ((size_t)gcol << 10) + (kc << 3));
            *(uint4*)(Wb + row * 2048 + ((kc ^ (row & 7)) << 4)) = v;
        }
    } else {
#pragma unroll 8
        for (int q = 0; q < 32; ++q) {
            int c = tid + (q << 8);
            int row = c >> 8, kc = c & 255;
            int gcol = ((row >> 3) << 10) + j0 + (row & 7);
            const u16* src = (kc < 128) ? (Wih2 + ((size_t)gcol << 10) + (kc << 3))
                                        : (Whh2 + ((size_t)gcol << 10) + ((kc - 128) << 3));
            uint4 v = *(const uint4*)src;
            *(uint4*)(Wb + row * 4096 + ((kc ^ (row & 7)) << 4)) = v;
        }
    }
    __syncthreads();

    const int arow = (wid << 4) + (lane & 15);
    const int jj16 = lane & 15;
    const int qhi = lane >> 5, qlo = (lane >> 4) & 1;

    if (isL1) {
        float creg[4];
#pragma unroll
        for (int r = 0; r < 4; ++r) {
            int b = (wid << 4) + ((lane >> 4) << 2) + r;
            creg[r] = c0[(b << 10) + j0 + jj16];
        }
        for (int i = 0; i < 255; ++i) {
            // X1 prefetch (issues before the poll; independent of h readiness)
            u64 xq[4];
#pragma unroll
            for (int r = 0; r < 4; ++r) {
                int b = (wid << 4) + ((lane >> 4) << 2) + r;
                xq[r] = *(const u64*)(X1 + ((size_t)((i << 6) + b) << 12) + ((j0 + jj16) << 2));
            }
            if (wid == 0) {
                long long g = 0;
                for (;;) {
                    u32 f = __hip_atomic_load(flg1 + (i << 6) + lane, __ATOMIC_RELAXED, __HIP_MEMORY_SCOPE_AGENT);
                    if (__all(f == 1u)) break;
                    __builtin_amdgcn_s_sleep(1);
                    if (++g > (1LL << 22)) break;  // safety net
                }
                asm volatile("" ::: "memory");
            }
            __syncthreads();
            const u16* abase = h1ring + ((size_t)i << 16) + ((size_t)qhi << 10) + ((size_t)arow << 4) + (qlo << 3);
            bf16x8 av[32];
#pragma unroll
            for (int kb = 0; kb < 32; ++kb) av[kb] = *(const bf16x8*)(abase + ((size_t)kb << 11));
            f32x4 acc[4] = {};
#pragma unroll
            for (int kb = 0; kb < 32; ++kb) {
                int kc = (kb << 2) + (lane >> 4);
#pragma unroll
                for (int g = 0; g < 4; ++g) {
                    int row = (g << 4) + jj16;
                    bf16x8 w = *(const bf16x8*)(Wb + row * 2048 + ((kc ^ (row & 7)) << 4));
                    acc[g] = __builtin_amdgcn_mfma_f32_16x16x32_bf16(av[kb], w, acc[g], 0, 0, 0);
                }
            }
#pragma unroll
            for (int r = 0; r < 4; ++r) {
                int b = (wid << 4) + ((lane >> 4) << 2) + r;
                float gi = acc[0][r] + bf2f((u16)(xq[r]));
                float gf = acc[1][r] + bf2f((u16)(xq[r] >> 16));
                float gg = acc[2][r] + bf2f((u16)(xq[r] >> 32));
                float go = acc[3][r] + bf2f((u16)(xq[r] >> 48));
                float cc = sigm(gf) * creg[r] + sigm(gi) * tanha(gg);
                creg[r] = cc;
                scr16[(b << 4) + jj16] = f2bf(sigm(go) * tanha(cc));
            }
            asm volatile("s_waitcnt lgkmcnt(0)" ::: "memory");
            // publish block-contiguous region: [slot i+1][jb=bid][b][jc]
            {
                u64 v = scr[(wid << 6) + lane];
                u16* dst = h1ring + ((size_t)(i + 1) << 16) + ((size_t)bid << 10) + (wid << 8) + (lane << 2);
                __hip_atomic_store((u64*)dst, v, __ATOMIC_RELAXED, __HIP_MEMORY_SCOPE_AGENT);
            }
            asm volatile("s_waitcnt vmcnt(0)" ::: "memory");
            __syncthreads();
            if (tid == 0)
                __hip_atomic_store(flg1 + ((i + 1) << 6) + bid, 1u, __ATOMIC_RELAXED, __HIP_MEMORY_SCOPE_AGENT);
        }
    } else {
        const int jb2 = bid - 64;
        float creg[4] = {0.f, 0.f, 0.f, 0.f};
        float b2v[4] = {0.f, 0.f, 0.f, 0.f};
        if ((lane & 15) < 8) {
            int jj = lane & 7;
#pragma unroll
            for (int g = 0; g < 4; ++g) b2v[g] = b2[(g << 10) + j0 + jj];
        }
        for (int s = 0; s < 255; ++s) {
            // ---- non-critical half: h1(s) is ready early (L1 runs ahead) ----
            if (wid == 0) {
                const u32* p1 = flg1 + ((s + 1) << 6) + lane;
                long long g = 0;
                for (;;) {
                    u32 a = __hip_atomic_load(p1, __ATOMIC_RELAXED, __HIP_MEMORY_SCOPE_AGENT);
                    if (__all(a == 1u)) break;
                    __builtin_amdgcn_s_sleep(1);
                    if (++g > (1LL << 22)) break;  // safety net
                }
                asm volatile("" ::: "memory");
            }
            __syncthreads();
            f32x4 acc[2] = {};
            {
                const u16* ab1 = h1ring + ((size_t)(s + 1) << 16) + ((size_t)qhi << 10) + ((size_t)arow << 4) + (qlo << 3);
                bf16x8 av[32];
#pragma unroll
                for (int kb = 0; kb < 32; ++kb) av[kb] = *(const bf16x8*)(ab1 + ((size_t)kb << 11));
#pragma unroll
                for (int kb = 0; kb < 32; ++kb) {
                    int kc = (kb << 2) + (lane >> 4);
#pragma unroll
                    for (int nt = 0; nt < 2; ++nt) {
                        int row = (nt << 4) + jj16;
                        bf16x8 w = *(const bf16x8*)(Wb + row * 4096 + ((kc ^ (row & 7)) << 4));
                        acc[nt] = __builtin_amdgcn_mfma_f32_16x16x32_bf16(av[kb], w, acc[nt], 0, 0, 0);
                    }
                }
            }
            // ---- serial half: wait h2(s-1), K-half 2 ----
            if (wid == 0) {
                const u64* p2 = (const u64*)(flg2 + (s << 7)) + lane;
                long long g = 0;
                for (;;) {
                    u64 b = __hip_atomic_load(p2, __ATOMIC_RELAXED, __HIP_MEMORY_SCOPE_AGENT);
                    if (__all(b == 0x0000000100000001ULL)) break;
                    __builtin_amdgcn_s_sleep(1);
                    if (++g > (1LL << 22)) break;  // safety net
                }
                asm volatile("" ::: "memory");
            }
            __syncthreads();
            {
                const u16* ab2 = h2ring + ((size_t)s << 16) + ((size_t)(lane >> 4) << 9) + ((size_t)arow << 3);
                bf16x8 bv[32];
#pragma unroll
                for (int kb = 0; kb < 32; ++kb) bv[kb] = *(const bf16x8*)(ab2 + ((size_t)kb << 11));
#pragma unroll
                for (int kb = 0; kb < 32; ++kb) {
                    int kc = ((kb + 32) << 2) + (lane >> 4);
#pragma unroll
                    for (int nt = 0; nt < 2; ++nt) {
                        int row = (nt << 4) + jj16;
                        bf16x8 w = *(const bf16x8*)(Wb + row * 4096 + ((kc ^ (row & 7)) << 4));
                        acc[nt] = __builtin_amdgcn_mfma_f32_16x16x32_bf16(bv[kb], w, acc[nt], 0, 0, 0);
                    }
                }
            }
            // gates: lane jj<8 holds {i,g}; partner jj+8 holds {f,o}
#pragma unroll
            for (int r = 0; r < 4; ++r) {
                float v0 = acc[0][r], v1 = acc[1][r];
                float p0 = __shfl_xor(v0, 8, 64);
                float p1 = __shfl_xor(v1, 8, 64);
                if ((lane & 15) < 8) {
                    int jj = lane & 7;
                    int b = (wid << 4) + ((lane >> 4) << 2) + r;
                    float gi = v0 + b2v[0];
                    float gf = p0 + b2v[1];
                    float gg = v1 + b2v[2];
                    float go = p1 + b2v[3];
                    float cc = sigm(gf) * creg[r] + sigm(gi) * tanha(gg);
                    creg[r] = cc;
                    scr16[(b << 3) + jj] = f2bf(sigm(go) * tanha(cc));
                }
            }
            asm volatile("s_waitcnt lgkmcnt(0)" ::: "memory");
            u64 v = 0;
            if (lane < 32) {
                v = scr[(wid << 5) + lane];
                // ring publish: [slot s+1][jb2][b][jc]
                u16* dst = h2ring + ((size_t)(s + 1) << 16) + ((size_t)jb2 << 9) + (wid << 7) + (lane << 2);
                __hip_atomic_store((u64*)dst, v, __ATOMIC_RELAXED, __HIP_MEMORY_SCOPE_AGENT);
            }
            asm volatile("s_waitcnt vmcnt(0)" ::: "memory");
            __syncthreads();
            if (tid == 0)
                __hip_atomic_store(flg2 + ((s + 1) << 7) + jb2, 1u, __ATOMIC_RELAXED, __HIP_MEMORY_SCOPE_AGENT);
            // H2 mirror AFTER the flag: off the critical path (consumed post-kernel)
            if (lane < 32)
                *(u64*)(H2 + ((size_t)s << 16) + ((size_t)jb2 << 9) + (wid << 7) + (lane << 2)) = v;
        }
    }
}

// ---------------- per-row log-softmax, in-place on d_out ----------------
__global__ __launch_bounds__(256) void lsm_kernel(float* __restrict__ out) {
    float* p = out + (size_t)blockIdx.x * 8000;
    const int tid = threadIdx.x;
    float4 v[8];
    float mx = -3.0e38f;
#pragma unroll
    for (int q = 0; q < 8; ++q) {
        int vi = tid + (q << 8);
        if (vi < 2000) {
            v[q] = *((const float4*)p + vi);
            mx = fmaxf(mx, fmaxf(fmaxf(v[q].x, v[q].y), fmaxf(v[q].z, v[q].w)));
        }
    }
#pragma unroll
    for (int o = 32; o >= 1; o >>= 1) mx = fmaxf(mx, __shfl_xor(mx, o, 64));
    __shared__ float red[8];
    if ((tid & 63) == 0) red[tid >> 6] = mx;
    __syncthreads();
    mx = fmaxf(fmaxf(red[0], red[1]), fmaxf(red[2], red[3]));
    float s = 0.f;
#pragma unroll
    for (int q = 0; q < 8; ++q) {
        int vi = tid + (q << 8);
        if (vi < 2000)
            s += __expf(v[q].x - mx) + __expf(v[q].y - mx) + __expf(v[q].z - mx) + __expf(v[q].w - mx);
    }
#pragma unroll
    for (int o = 32; o >= 1; o >>= 1) s += __shfl_xor(s, o, 64);
    if ((tid & 63) == 0) red[4 + (tid >> 6)] = s;
    __syncthreads();
    float lz = mx + logf(red[4] + red[5] + red[6] + red[7]);
#pragma unroll
    for (int q = 0; q < 8; ++q) {
        int vi = tid + (q << 8);
        if (vi < 2000) {
            float4 o4;
            o4.x = v[q].x - lz; o4.y = v[q].y - lz; o4.z = v[q].z - lz; o4.w = v[q].w - lz;
            *((float4*)p + vi) = o4;
        }
    }
}

// ---------------- host launch ----------------
extern "C" void kernel_launch(void* const* d_in, const int* in_sizes, int n_in,
                              void* d_out, int out_size, void* d_ws, size_t ws_size,
                              hipStream_t stream) {
    const int* gt = (const int*)d_in[0];
    const float* h0 = (const float*)d_in[1];
    const float* c0 = (const float*)d_in[2];
    const float* emb = (const float*)d_in[3];
    const float* Wih1 = (const float*)d_in[4];
    const float* Whh1 = (const float*)d_in[5];
    const float* bih1 = (const float*)d_in[6];
    const float* bhh1 = (const float*)d_in[7];
    const float* Wih2 = (const float*)d_in[8];
    const float* Whh2 = (const float*)d_in[9];
    const float* bih2 = (const float*)d_in[10];
    const float* bhh2 = (const float*)d_in[11];
    const float* Wout = (const float*)d_in[12];
    const float* bout = (const float*)d_in[13];

    char* w = (char*)d_ws;
    size_t off = 0;
    auto alloc = [&](size_t bytes) -> void* {
        void* p = (void*)(w + off);
        off = (off + bytes + 255) & ~(size_t)255;
        return p;
    };
    u32* flg1 = (u32*)alloc(16384 * 4);
    u32* flg2 = (u32*)alloc(32768 * 4);
    float* b1 = (float*)alloc(4096 * 4);
    float* b2 = (float*)alloc(4096 * 4);
    u16* embB = (u16*)alloc((size_t)8000 * 512 * 2);
    u16* Wih1B = (u16*)alloc((size_t)4096 * 512 * 2);
    u16* Whh1B = (u16*)alloc((size_t)4096 * 1024 * 2);
    u16* Wih2B = (u16*)alloc((size_t)4096 * 1024 * 2);
    u16* Whh2B = (u16*)alloc((size_t)4096 * 1024 * 2);
    u16* WoutB = (u16*)alloc((size_t)8192 * 1024 * 2);
    u16* H2 = (u16*)alloc((size_t)255 * 65536 * 2);

    // d_out (522 MB) scratch: X1 at 0 (134 MB), h rings at 136/168 MB — all dead
    // by the time phase C overwrites d_out.
    u16* X1 = (u16*)d_out;
    u16* h1ring = (u16*)((char*)d_out + (size_t)136 * 1024 * 1024);
    u16* h2ring = (u16*)((char*)d_out + (size_t)168 * 1024 * 1024);

    auto cvtN = [&](const float* s, u16* d, long long n) {
        unsigned blocks = (unsigned)((n / 4 + 255) / 256);
        cvt_kernel<<<blocks, 256, 0, stream>>>(s, d, n);
    };
    cvtN(emb, embB, (long long)8000 * 512);
    cvtN(Wih1, Wih1B, (long long)4096 * 512);
    cvtN(Whh1, Whh1B, (long long)4096 * 1024);
    cvtN(Wih2, Wih2B, (long long)4096 * 1024);
    cvtN(Whh2, Whh2B, (long long)4096 * 1024);
    cvt_wout_kernel<<<8192, 256, 0, stream>>>(Wout, WoutB);
    badd_kernel<<<16, 256, 0, stream>>>(bih1, bhh1, b1, 4096);
    badd_kernel<<<16, 256, 0, stream>>>(bih2, bhh2, b2, 4096);
    init_kernel<<<256, 256, 0, stream>>>(h0, h1ring, h2ring, flg1, flg2);

    // phase A: X1 = emb[gt] @ Wih1^T + b1  (bf16 gate-innermost, into d_out scratch)
    // grid: 32 x-panels * 128 y-tiles
    gemm_kernel<0, 512><<<32 * 128, 256, 0, stream>>>(embB, Wih1B, gt, b1, (void*)X1);

    // phase B: persistent dataflow recurrence
    {
        void* args[] = {(void*)&X1, (void*)&c0, (void*)&h1ring, (void*)&h2ring, (void*)&H2,
                        (void*)&Whh1B, (void*)&Wih2B, (void*)&Whh2B, (void*)&b2,
                        (void*)&flg1, (void*)&flg2};
        (void)hipLaunchCooperativeKernel(reinterpret_cast<const void*>(&lstm_kernel),
                                         dim3(192), dim3(256), args, 0, stream);
    }

    // phase C: logits = H2 @ Wout^T + bout  (fp32 into d_out)
    // grid: 64 x-panels * 128 y-tiles
    gemm_kernel<1, 1024><<<64 * 128, 256, 0, stream>>>(H2, WoutB, nullptr, bout, d_out);

    // log-softmax in place
    lsm_kernel<<<16320, 256, 0, stream>>>((float*)d_out);
}

// Round 13
// 2626.305 us; speedup vs baseline: 1.0355x; 1.0355x over previous
//
#include <hip/hip_runtime.h>

typedef unsigned short u16;
typedef unsigned int u32;
typedef unsigned long long u64;
typedef __attribute__((ext_vector_type(8))) short bf16x8;
typedef __attribute__((ext_vector_type(4))) float f32x4;

#define DEV __device__ __forceinline__

DEV float bf2f(u16 u) { unsigned v = ((unsigned)u) << 16; float f; __builtin_memcpy(&f, &v, 4); return f; }
DEV u16 f2bf(float f) { unsigned u; __builtin_memcpy(&u, &f, 4); u += 0x7FFFu + ((u >> 16) & 1u); return (u16)(u >> 16); }
DEV float sigm(float x) { return 1.f / (1.f + __expf(-x)); }
DEV float tanha(float x) { x = fminf(9.f, fmaxf(-9.f, x)); float t = __expf(2.f * x); return (t - 1.f) / (t + 1.f); }

// async global->LDS, 16B per lane; LDS dest is wave-uniform base + lane*16 (linear).
// XOR-swizzle pre-applied to the GLOBAL source address (involution; m104/m173 rule).
DEV void gload16(const void* g, void* l) {
    __builtin_amdgcn_global_load_lds((const __attribute__((address_space(1))) unsigned*)g,
                                     (__attribute__((address_space(3))) unsigned*)l, 16, 0, 0);
}

// ---------------- fused setup: all converts + bias adds + ring/flag init ----------
// Segmented quad-index space (each quad = 4 f32->bf16 elements or 4 u32 words):
//  [O0,O1) embB    [O1,O2) Wih1B   [O2,O3) Whh1B   [O3,O4) Wih2B   [O4,O5) Whh2B
//  [O5,O6) WoutB(8192x1024, zero-pad rows>=8000)   [O6,O7) b1|b2   [O7,O8) h-ring init
//  [O8,O9) flg1    [O9,OE) flg2
#define SO0 0LL
#define SO1 (SO0 + 1024000LL)
#define SO2 (SO1 + 524288LL)
#define SO3 (SO2 + 1048576LL)
#define SO4 (SO3 + 1048576LL)
#define SO5 (SO4 + 1048576LL)
#define SO6 (SO5 + 2097152LL)
#define SO7 (SO6 + 2048LL)
#define SO8 (SO7 + 16384LL)
#define SO9 (SO8 + 4096LL)
#define SOE (SO9 + 8192LL)

DEV void cvt4(const float* __restrict__ s, u16* __restrict__ d, long long i) {
    float4 v = *(const float4*)(s + i);
    uint2 o;
    o.x = (unsigned)f2bf(v.x) | ((unsigned)f2bf(v.y) << 16);
    o.y = (unsigned)f2bf(v.z) | ((unsigned)f2bf(v.w) << 16);
    *(uint2*)(d + i) = o;
}

__global__ __launch_bounds__(256) void setup_kernel(
    const float* __restrict__ emb, const float* __restrict__ Wih1, const float* __restrict__ Whh1,
    const float* __restrict__ Wih2, const float* __restrict__ Whh2, const float* __restrict__ Wout,
    const float* __restrict__ bih1, const float* __restrict__ bhh1, const float* __restrict__ bih2,
    const float* __restrict__ bhh2, const float* __restrict__ h0,
    u16* __restrict__ embB, u16* __restrict__ Wih1B, u16* __restrict__ Whh1B, u16* __restrict__ Wih2B,
    u16* __restrict__ Whh2B, u16* __restrict__ WoutB, float* __restrict__ b1, float* __restrict__ b2,
    u16* __restrict__ h1ring, u16* __restrict__ h2ring, u32* __restrict__ flg1, u32* __restrict__ flg2) {
    long long q = (long long)blockIdx.x * 256 + threadIdx.x;
    if (q < SO1) {
        cvt4(emb, embB, (q - SO0) << 2);
    } else if (q < SO2) {
        cvt4(Wih1, Wih1B, (q - SO1) << 2);
    } else if (q < SO3) {
        cvt4(Whh1, Whh1B, (q - SO2) << 2);
    } else if (q < SO4) {
        cvt4(Wih2, Wih2B, (q - SO3) << 2);
    } else if (q < SO5) {
        cvt4(Whh2, Whh2B, (q - SO4) << 2);
    } else if (q < SO6) {
        long long i = (q - SO5) << 2;
        int row = (int)(i >> 10), col = (int)(i & 1023);
        uint2 o;
        if (row < 8000) {
            float4 v = *(const float4*)(Wout + (size_t)row * 1024 + col);
            o.x = (unsigned)f2bf(v.x) | ((unsigned)f2bf(v.y) << 16);
            o.y = (unsigned)f2bf(v.z) | ((unsigned)f2bf(v.w) << 16);
        } else { o.x = 0u; o.y = 0u; }
        *(uint2*)(WoutB + i) = o;
    } else if (q < SO7) {
        int i = (int)(q - SO6) << 2;
        if (i < 4096) {
            float4 a = *(const float4*)(bih1 + i), b = *(const float4*)(bhh1 + i);
            float4 o; o.x = a.x + b.x; o.y = a.y + b.y; o.z = a.z + b.z; o.w = a.w + b.w;
            *(float4*)(b1 + i) = o;
        } else {
            int j = i - 4096;
            float4 a = *(const float4*)(bih2 + j), b = *(const float4*)(bhh2 + j);
            float4 o; o.x = a.x + b.x; o.y = a.y + b.y; o.z = a.z + b.z; o.w = a.w + b.w;
            *(float4*)(b2 + j) = o;
        }
    } else if (q < SO8) {
        int i = (int)(q - SO7) << 2;  // 4 consecutive elements, same b, cols col..col+3
        int b = i >> 10, col = i & 1023;
        float4 v = *(const float4*)(h0 + i);
        u64 hv = (u64)f2bf(v.x) | ((u64)f2bf(v.y) << 16) | ((u64)f2bf(v.z) << 32) | ((u64)f2bf(v.w) << 48);
        *(u64*)(h1ring + ((col >> 4) << 10) + (b << 4) + (col & 15)) = hv;  // slot0 = h0
        *(u64*)(h2ring + i) = 0;                                           // slot0 = 0
    } else if (q < SO9) {
        int i = (int)(q - SO8) << 2;
        uint4 o;
        o.x = (i < 64) ? 1u : 0u; o.y = (i + 1 < 64) ? 1u : 0u;
        o.z = (i + 2 < 64) ? 1u : 0u; o.w = (i + 3 < 64) ? 1u : 0u;
        *(uint4*)(flg1 + i) = o;
    } else if (q < SOE) {
        int i = (int)(q - SO9) << 2;
        uint4 o;
        o.x = (i < 128) ? 1u : 0u; o.y = (i + 1 < 128) ? 1u : 0u;
        o.z = (i + 2 < 128) ? 1u : 0u; o.w = (i + 3 < 128) ? 1u : 0u;
        *(uint4*)(flg2 + i) = o;
    }
}

// ---------------- generic 64x256-tile bf16 GEMM (C = A @ B^T + bias) ----------------
// Staging via global_load_lds width-16: linear LDS dest (wave-uniform base + lane*16),
// swizzle pre-applied to the global source. Reads stay XOR-swizzled.
// MODE 0: phase A, K=512, A-row = emb[gt]; out X1 gate-innermost: X1[(t*64+m)*4096 + j*4 + g].
// MODE 1: phase C, K=1024, A-row = H2 block-layout [t][k>>3][row][k&7]; out f32 logits.
template <int MODE, int K>
__global__ __launch_bounds__(256) void gemm_kernel(const u16* __restrict__ Asrc, const u16* __restrict__ Bmat,
                                                   const int* __restrict__ gt, const float* __restrict__ bias,
                                                   void* __restrict__ outp) {
    __shared__ uint4 AldsV[512];   // 64 x 64 bf16 = 8 KiB
    __shared__ uint4 BldsV[2048];  // 256 x 64 bf16 = 32 KiB
    char* Al = (char*)AldsV;
    char* Bl = (char*)BldsV;
    const int t = blockIdx.y;
    const int n0 = blockIdx.x << 8;
    const int tid = threadIdx.x;
    const int lane = tid & 63, wid = tid >> 6;

    // hoisted per-chunk A-row metadata
    int tokq[2];
#pragma unroll
    for (int q = 0; q < 2; ++q) {
        int c = tid + (q << 8);
        if (MODE == 0) tokq[q] = gt[(c >> 3) * 256 + t];
    }

    f32x4 acc[4][4] = {};

    for (int k0 = 0; k0 < K; k0 += 64) {
        // ---- stage A: 512 chunks of 16B ----
#pragma unroll
        for (int q = 0; q < 2; ++q) {
            int c = tid + (q << 8);
            int row = c >> 3, kc = c & 7;
            int kcs = kc ^ (row & 7);  // swizzle on SOURCE; dest linear
            const u16* src;
            if (MODE == 0) {
                src = Asrc + (size_t)tokq[q] * 512 + k0 + (kcs << 3);
            } else {
                src = Asrc + ((size_t)t << 16) + ((size_t)((k0 >> 3) + kcs) << 9) + (row << 3);
            }
            gload16(src, Al + (q << 12) + (wid << 10));
        }
        // ---- stage B: 2048 chunks ----
#pragma unroll
        for (int q = 0; q < 8; ++q) {
            int c = tid + (q << 8);
            int row = c >> 3, kc = c & 7;
            int kcs = kc ^ (row & 7);
            gload16(Bmat + (size_t)(n0 + row) * K + k0 + (kcs << 3), Bl + (q << 12) + (wid << 10));
        }
        asm volatile("s_waitcnt vmcnt(0)" ::: "memory");
        __syncthreads();
#pragma unroll
        for (int kb2 = 0; kb2 < 2; ++kb2) {
            bf16x8 af[4], bf[4];
#pragma unroll
            for (int mt = 0; mt < 4; ++mt) {
                int row = (mt << 4) + (lane & 15);
                int kc = (kb2 << 2) + (lane >> 4);
                af[mt] = *(const bf16x8*)(Al + row * 128 + ((kc ^ (row & 7)) << 4));
            }
#pragma unroll
            for (int nt = 0; nt < 4; ++nt) {
                int row = (wid << 6) + (nt << 4) + (lane & 15);
                int kc = (kb2 << 2) + (lane >> 4);
                bf[nt] = *(const bf16x8*)(Bl + row * 128 + ((kc ^ (row & 7)) << 4));
            }
#pragma unroll
            for (int mt = 0; mt < 4; ++mt)
#pragma unroll
                for (int nt = 0; nt < 4; ++nt)
                    acc[mt][nt] = __builtin_amdgcn_mfma_f32_16x16x32_bf16(af[mt], bf[nt], acc[mt][nt], 0, 0, 0);
        }
        __syncthreads();
    }

#pragma unroll
    for (int nt = 0; nt < 4; ++nt) {
        int n = n0 + (wid << 6) + (nt << 4) + (lane & 15);
        float bv = 0.f;
        if (MODE == 0) bv = bias[n];
        else if (n < 8000) bv = bias[n];
#pragma unroll
        for (int mt = 0; mt < 4; ++mt) {
#pragma unroll
            for (int r = 0; r < 4; ++r) {
                int ml = (mt << 4) + ((lane >> 4) << 2) + r;
                float v = acc[mt][nt][r] + bv;
                if (MODE == 0) {
                    ((u16*)outp)[((size_t)((t << 6) + ml) << 12) + ((n & 1023) << 2) + (n >> 10)] = f2bf(v);
                } else {
                    if (n < 8000) ((float*)outp)[(size_t)(ml * 255 + t) * 8000 + n] = v;
                }
            }
        }
    }
}

// ---------------- persistent dataflow 2-layer LSTM (flag-based, split L2 loop) ----
// blocks 0..63:  layer1, j0=bid*16.  blocks 64..191: layer2, j0=(bid-64)*8.
// Publish: sc1 data stores -> vmcnt(0) -> __syncthreads -> ONE flag store/block.
// L2 loop split: {poll flg1[s+1] -> h1 read + Wih2-half MFMA} BEFORE the serial
// {poll flg2[s] -> h2 read + Whh2-half MFMA -> act -> publish}. H2 mirror store
// issues AFTER the flag (off the critical path; consumed only post-kernel).
__global__ __launch_bounds__(256, 1) void lstm_kernel(const u16* __restrict__ X1, const float* __restrict__ c0,
                                                      u16* __restrict__ h1ring, u16* __restrict__ h2ring,
                                                      u16* __restrict__ H2, const u16* __restrict__ Whh1,
                                                      const u16* __restrict__ Wih2, const u16* __restrict__ Whh2,
                                                      const float* __restrict__ b2, u32* __restrict__ flg1,
                                                      u32* __restrict__ flg2) {
    __shared__ uint4 WldsV[8192];  // 128 KiB weight slice
    __shared__ u64 scr[256];       // repack scratch (wave-private regions)
    char* Wb = (char*)WldsV;
    u16* scr16 = (u16*)scr;
    const int tid = threadIdx.x;
    const int lane = tid & 63, wid = tid >> 6;
    const int bid = blockIdx.x;
    const bool isL1 = (bid < 64);
    const int j0 = isL1 ? (bid << 4) : ((bid - 64) << 3);

    // ---- stage weights into LDS (XOR-swizzled rows) ----
    if (isL1) {
#pragma unroll 8
        for (int q = 0; q < 32; ++q) {
            int c = tid + (q << 8);
            int row = c >> 7, kc = c & 127;
            int gcol = ((row >> 4) << 10) + j0 + (row & 15);
            uint4 v = *(const uint4*)(Whh1 + ((size_t)gcol << 10) + (kc << 3));
            *(uint4*)(Wb + row * 2048 + ((kc ^ (row & 7)) << 4)) = v;
        }
    } else {
#pragma unroll 8
        for (int q = 0; q < 32; ++q) {
            int c = tid + (q << 8);
            int row = c >> 8, kc = c & 255;
            int gcol = ((row >> 3) << 10) + j0 + (row & 7);
            const u16* src = (kc < 128) ? (Wih2 + ((size_t)gcol << 10) + (kc << 3))
                                        : (Whh2 + ((size_t)gcol << 10) + ((kc - 128) << 3));
            uint4 v = *(const uint4*)src;
            *(uint4*)(Wb + row * 4096 + ((kc ^ (row & 7)) << 4)) = v;
        }
    }
    __syncthreads();

    const int arow = (wid << 4) + (lane & 15);
    const int jj16 = lane & 15;
    const int qhi = lane >> 5, qlo = (lane >> 4) & 1;

    if (isL1) {
        float creg[4];
#pragma unroll
        for (int r = 0; r < 4; ++r) {
            int b = (wid << 4) + ((lane >> 4) << 2) + r;
            creg[r] = c0[(b << 10) + j0 + jj16];
        }
        for (int i = 0; i < 255; ++i) {
            // X1 prefetch (issues before the poll; independent of h readiness)
            u64 xq[4];
#pragma unroll
            for (int r = 0; r < 4; ++r) {
                int b = (wid << 4) + ((lane >> 4) << 2) + r;
                xq[r] = *(const u64*)(X1 + ((size_t)((i << 6) + b) << 12) + ((j0 + jj16) << 2));
            }
            if (wid == 0) {
                long long g = 0;
                for (;;) {
                    u32 f = __hip_atomic_load(flg1 + (i << 6) + lane, __ATOMIC_RELAXED, __HIP_MEMORY_SCOPE_AGENT);
                    if (__all(f == 1u)) break;
                    __builtin_amdgcn_s_sleep(1);
                    if (++g > (1LL << 22)) break;  // safety net
                }
                asm volatile("" ::: "memory");
            }
            __syncthreads();
            const u16* abase = h1ring + ((size_t)i << 16) + ((size_t)qhi << 10) + ((size_t)arow << 4) + (qlo << 3);
            bf16x8 av[32];
#pragma unroll
            for (int kb = 0; kb < 32; ++kb) av[kb] = *(const bf16x8*)(abase + ((size_t)kb << 11));
            f32x4 acc[4] = {};
#pragma unroll
            for (int kb = 0; kb < 32; ++kb) {
                int kc = (kb << 2) + (lane >> 4);
#pragma unroll
                for (int g = 0; g < 4; ++g) {
                    int row = (g << 4) + jj16;
                    bf16x8 w = *(const bf16x8*)(Wb + row * 2048 + ((kc ^ (row & 7)) << 4));
                    acc[g] = __builtin_amdgcn_mfma_f32_16x16x32_bf16(av[kb], w, acc[g], 0, 0, 0);
                }
            }
#pragma unroll
            for (int r = 0; r < 4; ++r) {
                int b = (wid << 4) + ((lane >> 4) << 2) + r;
                float gi = acc[0][r] + bf2f((u16)(xq[r]));
                float gf = acc[1][r] + bf2f((u16)(xq[r] >> 16));
                float gg = acc[2][r] + bf2f((u16)(xq[r] >> 32));
                float go = acc[3][r] + bf2f((u16)(xq[r] >> 48));
                float cc = sigm(gf) * creg[r] + sigm(gi) * tanha(gg);
                creg[r] = cc;
                scr16[(b << 4) + jj16] = f2bf(sigm(go) * tanha(cc));
            }
            asm volatile("s_waitcnt lgkmcnt(0)" ::: "memory");
            // publish block-contiguous region: [slot i+1][jb=bid][b][jc]
            {
                u64 v = scr[(wid << 6) + lane];
                u16* dst = h1ring + ((size_t)(i + 1) << 16) + ((size_t)bid << 10) + (wid << 8) + (lane << 2);
                __hip_atomic_store((u64*)dst, v, __ATOMIC_RELAXED, __HIP_MEMORY_SCOPE_AGENT);
            }
            asm volatile("s_waitcnt vmcnt(0)" ::: "memory");
            __syncthreads();
            if (tid == 0)
                __hip_atomic_store(flg1 + ((i + 1) << 6) + bid, 1u, __ATOMIC_RELAXED, __HIP_MEMORY_SCOPE_AGENT);
        }
    } else {
        const int jb2 = bid - 64;
        float creg[4] = {0.f, 0.f, 0.f, 0.f};
        float b2v[4] = {0.f, 0.f, 0.f, 0.f};
        if ((lane & 15) < 8) {
            int jj = lane & 7;
#pragma unroll
            for (int g = 0; g < 4; ++g) b2v[g] = b2[(g << 10) + j0 + jj];
        }
        for (int s = 0; s < 255; ++s) {
            // ---- non-critical half: h1(s) is ready early (L1 runs ahead) ----
            if (wid == 0) {
                const u32* p1 = flg1 + ((s + 1) << 6) + lane;
                long long g = 0;
                for (;;) {
                    u32 a = __hip_atomic_load(p1, __ATOMIC_RELAXED, __HIP_MEMORY_SCOPE_AGENT);
                    if (__all(a == 1u)) break;
                    __builtin_amdgcn_s_sleep(1);
                    if (++g > (1LL << 22)) break;  // safety net
                }
                asm volatile("" ::: "memory");
            }
            __syncthreads();
            f32x4 acc[2] = {};
            {
                const u16* ab1 = h1ring + ((size_t)(s + 1) << 16) + ((size_t)qhi << 10) + ((size_t)arow << 4) + (qlo << 3);
                bf16x8 av[32];
#pragma unroll
                for (int kb = 0; kb < 32; ++kb) av[kb] = *(const bf16x8*)(ab1 + ((size_t)kb << 11));
#pragma unroll
                for (int kb = 0; kb < 32; ++kb) {
                    int kc = (kb << 2) + (lane >> 4);
#pragma unroll
                    for (int nt = 0; nt < 2; ++nt) {
                        int row = (nt << 4) + jj16;
                        bf16x8 w = *(const bf16x8*)(Wb + row * 4096 + ((kc ^ (row & 7)) << 4));
                        acc[nt] = __builtin_amdgcn_mfma_f32_16x16x32_bf16(av[kb], w, acc[nt], 0, 0, 0);
                    }
                }
            }
            // ---- serial half: wait h2(s-1), K-half 2 ----
            if (wid == 0) {
                const u64* p2 = (const u64*)(flg2 + (s << 7)) + lane;
                long long g = 0;
                for (;;) {
                    u64 b = __hip_atomic_load(p2, __ATOMIC_RELAXED, __HIP_MEMORY_SCOPE_AGENT);
                    if (__all(b == 0x0000000100000001ULL)) break;
                    __builtin_amdgcn_s_sleep(1);
                    if (++g > (1LL << 22)) break;  // safety net
                }
                asm volatile("" ::: "memory");
            }
            __syncthreads();
            {
                const u16* ab2 = h2ring + ((size_t)s << 16) + ((size_t)(lane >> 4) << 9) + ((size_t)arow << 3);
                bf16x8 bv[32];
#pragma unroll
                for (int kb = 0; kb < 32; ++kb) bv[kb] = *(const bf16x8*)(ab2 + ((size_t)kb << 11));
#pragma unroll
                for (int kb = 0; kb < 32; ++kb) {
                    int kc = ((kb + 32) << 2) + (lane >> 4);
#pragma unroll
                    for (int nt = 0; nt < 2; ++nt) {
                        int row = (nt << 4) + jj16;
                        bf16x8 w = *(const bf16x8*)(Wb + row * 4096 + ((kc ^ (row & 7)) << 4));
                        acc[nt] = __builtin_amdgcn_mfma_f32_16x16x32_bf16(bv[kb], w, acc[nt], 0, 0, 0);
                    }
                }
            }
            // gates: lane jj<8 holds {i,g}; partner jj+8 holds {f,o}
#pragma unroll
            for (int r = 0; r < 4; ++r) {
                float v0 = acc[0][r], v1 = acc[1][r];
                float p0 = __shfl_xor(v0, 8, 64);
                float p1 = __shfl_xor(v1, 8, 64);
                if ((lane & 15) < 8) {
                    int jj = lane & 7;
                    int b = (wid << 4) + ((lane >> 4) << 2) + r;
                    float gi = v0 + b2v[0];
                    float gf = p0 + b2v[1];
                    float gg = v1 + b2v[2];
                    float go = p1 + b2v[3];
                    float cc = sigm(gf) * creg[r] + sigm(gi) * tanha(gg);
                    creg[r] = cc;
                    scr16[(b << 3) + jj] = f2bf(sigm(go) * tanha(cc));
                }
            }
            asm volatile("s_waitcnt lgkmcnt(0)" ::: "memory");
            u64 v = 0;
            if (lane < 32) {
                v = scr[(wid << 5) + lane];
                // ring publish: [slot s+1][jb2][b][jc]
                u16* dst = h2ring + ((size_t)(s + 1) << 16) + ((size_t)jb2 << 9) + (wid << 7) + (lane << 2);
                __hip_atomic_store((u64*)dst, v, __ATOMIC_RELAXED, __HIP_MEMORY_SCOPE_AGENT);
            }
            asm volatile("s_waitcnt vmcnt(0)" ::: "memory");
            __syncthreads();
            if (tid == 0)
                __hip_atomic_store(flg2 + ((s + 1) << 7) + jb2, 1u, __ATOMIC_RELAXED, __HIP_MEMORY_SCOPE_AGENT);
            // H2 mirror AFTER the flag: off the critical path (consumed post-kernel)
            if (lane < 32)
                *(u64*)(H2 + ((size_t)s << 16) + ((size_t)jb2 << 9) + (wid << 7) + (lane << 2)) = v;
        }
    }
}

// ---------------- per-row log-softmax, in-place on d_out ----------------
__global__ __launch_bounds__(256) void lsm_kernel(float* __restrict__ out) {
    float* p = out + (size_t)blockIdx.x * 8000;
    const int tid = threadIdx.x;
    float4 v[8];
    float mx = -3.0e38f;
#pragma unroll
    for (int q = 0; q < 8; ++q) {
        int vi = tid + (q << 8);
        if (vi < 2000) {
            v[q] = *((const float4*)p + vi);
            mx = fmaxf(mx, fmaxf(fmaxf(v[q].x, v[q].y), fmaxf(v[q].z, v[q].w)));
        }
    }
#pragma unroll
    for (int o = 32; o >= 1; o >>= 1) mx = fmaxf(mx, __shfl_xor(mx, o, 64));
    __shared__ float red[8];
    if ((tid & 63) == 0) red[tid >> 6] = mx;
    __syncthreads();
    mx = fmaxf(fmaxf(red[0], red[1]), fmaxf(red[2], red[3]));
    float s = 0.f;
#pragma unroll
    for (int q = 0; q < 8; ++q) {
        int vi = tid + (q << 8);
        if (vi < 2000)
            s += __expf(v[q].x - mx) + __expf(v[q].y - mx) + __expf(v[q].z - mx) + __expf(v[q].w - mx);
    }
#pragma unroll
    for (int o = 32; o >= 1; o >>= 1) s += __shfl_xor(s, o, 64);
    if ((tid & 63) == 0) red[4 + (tid >> 6)] = s;
    __syncthreads();
    float lz = mx + logf(red[4] + red[5] + red[6] + red[7]);
#pragma unroll
    for (int q = 0; q < 8; ++q) {
        int vi = tid + (q << 8);
        if (vi < 2000) {
            float4 o4;
            o4.x = v[q].x - lz; o4.y = v[q].y - lz; o4.z = v[q].z - lz; o4.w = v[q].w - lz;
            *((float4*)p + vi) = o4;
        }
    }
}

// ---------------- host launch ----------------
extern "C" void kernel_launch(void* const* d_in, const int* in_sizes, int n_in,
                              void* d_out, int out_size, void* d_ws, size_t ws_size,
                              hipStream_t stream) {
    const int* gt = (const int*)d_in[0];
    const float* h0 = (const float*)d_in[1];
    const float* c0 = (const float*)d_in[2];
    const float* emb = (const float*)d_in[3];
    const float* Wih1 = (const float*)d_in[4];
    const float* Whh1 = (const float*)d_in[5];
    const float* bih1 = (const float*)d_in[6];
    const float* bhh1 = (const float*)d_in[7];
    const float* Wih2 = (const float*)d_in[8];
    const float* Whh2 = (const float*)d_in[9];
    const float* bih2 = (const float*)d_in[10];
    const float* bhh2 = (const float*)d_in[11];
    const float* Wout = (const float*)d_in[12];
    const float* bout = (const float*)d_in[13];

    char* w = (char*)d_ws;
    size_t off = 0;
    auto alloc = [&](size_t bytes) -> void* {
        void* p = (void*)(w + off);
        off = (off + bytes + 255) & ~(size_t)255;
        return p;
    };
    u32* flg1 = (u32*)alloc(16384 * 4);
    u32* flg2 = (u32*)alloc(32768 * 4);
    float* b1 = (float*)alloc(4096 * 4);
    float* b2 = (float*)alloc(4096 * 4);
    u16* embB = (u16*)alloc((size_t)8000 * 512 * 2);
    u16* Wih1B = (u16*)alloc((size_t)4096 * 512 * 2);
    u16* Whh1B = (u16*)alloc((size_t)4096 * 1024 * 2);
    u16* Wih2B = (u16*)alloc((size_t)4096 * 1024 * 2);
    u16* Whh2B = (u16*)alloc((size_t)4096 * 1024 * 2);
    u16* WoutB = (u16*)alloc((size_t)8192 * 1024 * 2);
    u16* H2 = (u16*)alloc((size_t)255 * 65536 * 2);

    // d_out (522 MB) scratch: X1 at 0 (134 MB), h rings at 136/168 MB — all dead
    // by the time phase C overwrites d_out.
    u16* X1 = (u16*)d_out;
    u16* h1ring = (u16*)((char*)d_out + (size_t)136 * 1024 * 1024);
    u16* h2ring = (u16*)((char*)d_out + (size_t)168 * 1024 * 1024);

    // fused setup: all f32->bf16 converts + bias adds + ring/flag init (1 launch)
    {
        long long total = SOE;
        unsigned blocks = (unsigned)((total + 255) / 256);
        setup_kernel<<<blocks, 256, 0, stream>>>(emb, Wih1, Whh1, Wih2, Whh2, Wout,
                                                 bih1, bhh1, bih2, bhh2, h0,
                                                 embB, Wih1B, Whh1B, Wih2B, Whh2B, WoutB,
                                                 b1, b2, h1ring, h2ring, flg1, flg2);
    }

    // phase A: X1 = emb[gt] @ Wih1^T + b1  (bf16 gate-innermost, into d_out scratch)
    gemm_kernel<0, 512><<<dim3(16, 255), 256, 0, stream>>>(embB, Wih1B, gt, b1, (void*)X1);

    // phase B: persistent dataflow recurrence
    {
        void* args[] = {(void*)&X1, (void*)&c0, (void*)&h1ring, (void*)&h2ring, (void*)&H2,
                        (void*)&Whh1B, (void*)&Wih2B, (void*)&Whh2B, (void*)&b2,
                        (void*)&flg1, (void*)&flg2};
        (void)hipLaunchCooperativeKernel(reinterpret_cast<const void*>(&lstm_kernel),
                                         dim3(192), dim3(256), args, 0, stream);
    }

    // phase C: logits = H2 @ Wout^T + bout  (fp32 into d_out)
    gemm_kernel<1, 1024><<<dim3(32, 255), 256, 0, stream>>>(H2, WoutB, nullptr, bout, d_out);

    // log-softmax in place
    lsm_kernel<<<16320, 256, 0, stream>>>((float*)d_out);
}

// Round 15
// 2511.124 us; speedup vs baseline: 1.0829x; 1.0459x over previous
//
#include <hip/hip_runtime.h>

typedef unsigned short u16;
typedef unsigned int u32;
typedef unsigned long long u64;
typedef __attribute__((ext_vector_type(8))) short bf16x8;
typedef __attribute__((ext_vector_type(4))) float f32x4;

#define DEV __device__ __forceinline__

DEV float bf2f(u16 u) { unsigned v = ((unsigned)u) << 16; float f; __builtin_memcpy(&f, &v, 4); return f; }
DEV u16 f2bf(float f) { unsigned u; __builtin_memcpy(&u, &f, 4); u += 0x7FFFu + ((u >> 16) & 1u); return (u16)(u >> 16); }
DEV float sigm(float x) { return 1.f / (1.f + __expf(-x)); }
DEV float tanha(float x) { x = fminf(9.f, fmaxf(-9.f, x)); float t = __expf(2.f * x); return (t - 1.f) / (t + 1.f); }

// async global->LDS, 16B per lane; LDS dest is wave-uniform base + lane*16 (linear).
// XOR-swizzle pre-applied to the GLOBAL source address (involution; m104/m173 rule).
DEV void gload16(const void* g, void* l) {
    __builtin_amdgcn_global_load_lds((const __attribute__((address_space(1))) unsigned*)g,
                                     (__attribute__((address_space(3))) unsigned*)l, 16, 0, 0);
}

// bf16 logits live INSIDE each f32 output row's own slot: row r's bf16 data at byte
// 32000*r (stride 16000 u16, first 8000 used). Each lsm block reads only its own
// slot and writes only its own slot -> zero cross-block aliasing (fixes R14's race);
// self-overlap safe: all loads are consumed into registers (forced by the max
// reduction before the first __syncthreads) before any store.

// ---------------- fused setup: all converts + bias adds + ring/flag init ----------
// Segmented quad-index space (each quad = 4 f32->bf16 elements or 4 u32 words):
//  [O0,O1) embB    [O1,O2) Wih1B   [O2,O3) Whh1B   [O3,O4) Wih2B   [O4,O5) Whh2B
//  [O5,O6) WoutB(8192x1024, zero-pad rows>=8000)   [O6,O7) b1|b2   [O7,O8) h-ring init
//  [O8,O9) flg1    [O9,OE) flg2
#define SO0 0LL
#define SO1 (SO0 + 1024000LL)
#define SO2 (SO1 + 524288LL)
#define SO3 (SO2 + 1048576LL)
#define SO4 (SO3 + 1048576LL)
#define SO5 (SO4 + 1048576LL)
#define SO6 (SO5 + 2097152LL)
#define SO7 (SO6 + 2048LL)
#define SO8 (SO7 + 16384LL)
#define SO9 (SO8 + 4096LL)
#define SOE (SO9 + 8192LL)

DEV void cvt4(const float* __restrict__ s, u16* __restrict__ d, long long i) {
    float4 v = *(const float4*)(s + i);
    uint2 o;
    o.x = (unsigned)f2bf(v.x) | ((unsigned)f2bf(v.y) << 16);
    o.y = (unsigned)f2bf(v.z) | ((unsigned)f2bf(v.w) << 16);
    *(uint2*)(d + i) = o;
}

__global__ __launch_bounds__(256) void setup_kernel(
    const float* __restrict__ emb, const float* __restrict__ Wih1, const float* __restrict__ Whh1,
    const float* __restrict__ Wih2, const float* __restrict__ Whh2, const float* __restrict__ Wout,
    const float* __restrict__ bih1, const float* __restrict__ bhh1, const float* __restrict__ bih2,
    const float* __restrict__ bhh2, const float* __restrict__ h0,
    u16* __restrict__ embB, u16* __restrict__ Wih1B, u16* __restrict__ Whh1B, u16* __restrict__ Wih2B,
    u16* __restrict__ Whh2B, u16* __restrict__ WoutB, float* __restrict__ b1, float* __restrict__ b2,
    u16* __restrict__ h1ring, u16* __restrict__ h2ring, u32* __restrict__ flg1, u32* __restrict__ flg2) {
    long long q = (long long)blockIdx.x * 256 + threadIdx.x;
    if (q < SO1) {
        cvt4(emb, embB, (q - SO0) << 2);
    } else if (q < SO2) {
        cvt4(Wih1, Wih1B, (q - SO1) << 2);
    } else if (q < SO3) {
        cvt4(Whh1, Whh1B, (q - SO2) << 2);
    } else if (q < SO4) {
        cvt4(Wih2, Wih2B, (q - SO3) << 2);
    } else if (q < SO5) {
        cvt4(Whh2, Whh2B, (q - SO4) << 2);
    } else if (q < SO6) {
        long long i = (q - SO5) << 2;
        int row = (int)(i >> 10), col = (int)(i & 1023);
        uint2 o;
        if (row < 8000) {
            float4 v = *(const float4*)(Wout + (size_t)row * 1024 + col);
            o.x = (unsigned)f2bf(v.x) | ((unsigned)f2bf(v.y) << 16);
            o.y = (unsigned)f2bf(v.z) | ((unsigned)f2bf(v.w) << 16);
        } else { o.x = 0u; o.y = 0u; }
        *(uint2*)(WoutB + i) = o;
    } else if (q < SO7) {
        int i = (int)(q - SO6) << 2;
        if (i < 4096) {
            float4 a = *(const float4*)(bih1 + i), b = *(const float4*)(bhh1 + i);
            float4 o; o.x = a.x + b.x; o.y = a.y + b.y; o.z = a.z + b.z; o.w = a.w + b.w;
            *(float4*)(b1 + i) = o;
        } else {
            int j = i - 4096;
            float4 a = *(const float4*)(bih2 + j), b = *(const float4*)(bhh2 + j);
            float4 o; o.x = a.x + b.x; o.y = a.y + b.y; o.z = a.z + b.z; o.w = a.w + b.w;
            *(float4*)(b2 + j) = o;
        }
    } else if (q < SO8) {
        int i = (int)(q - SO7) << 2;  // 4 consecutive elements, same b, cols col..col+3
        int b = i >> 10, col = i & 1023;
        float4 v = *(const float4*)(h0 + i);
        u64 hv = (u64)f2bf(v.x) | ((u64)f2bf(v.y) << 16) | ((u64)f2bf(v.z) << 32) | ((u64)f2bf(v.w) << 48);
        *(u64*)(h1ring + ((col >> 4) << 10) + (b << 4) + (col & 15)) = hv;  // slot0 = h0
        *(u64*)(h2ring + i) = 0;                                           // slot0 = 0
    } else if (q < SO9) {
        int i = (int)(q - SO8) << 2;
        uint4 o;
        o.x = (i < 64) ? 1u : 0u; o.y = (i + 1 < 64) ? 1u : 0u;
        o.z = (i + 2 < 64) ? 1u : 0u; o.w = (i + 3 < 64) ? 1u : 0u;
        *(uint4*)(flg1 + i) = o;
    } else if (q < SOE) {
        int i = (int)(q - SO9) << 2;
        uint4 o;
        o.x = (i < 128) ? 1u : 0u; o.y = (i + 1 < 128) ? 1u : 0u;
        o.z = (i + 2 < 128) ? 1u : 0u; o.w = (i + 3 < 128) ? 1u : 0u;
        *(uint4*)(flg2 + i) = o;
    }
}

// ---------------- generic 64x256-tile bf16 GEMM (C = A @ B^T + bias) ----------------
// Staging via global_load_lds width-16: linear LDS dest (wave-uniform base + lane*16),
// swizzle pre-applied to the global source. Reads stay XOR-swizzled.
// MODE 0: phase A, K=512, A-row = emb[gt]; out X1 gate-innermost: X1[(t*64+m)*4096 + j*4 + g].
// MODE 1: phase C, K=1024, A-row = H2 block-layout [t][k>>3][row][k&7]; out BF16 logits
//         into d_out at row slot stride 16000 u16 (row = b*255+t, first 8000 u16 used).
template <int MODE, int K>
__global__ __launch_bounds__(256) void gemm_kernel(const u16* __restrict__ Asrc, const u16* __restrict__ Bmat,
                                                   const int* __restrict__ gt, const float* __restrict__ bias,
                                                   void* __restrict__ outp) {
    __shared__ uint4 AldsV[512];   // 64 x 64 bf16 = 8 KiB
    __shared__ uint4 BldsV[2048];  // 256 x 64 bf16 = 32 KiB
    char* Al = (char*)AldsV;
    char* Bl = (char*)BldsV;
    const int t = blockIdx.y;
    const int n0 = blockIdx.x << 8;
    const int tid = threadIdx.x;
    const int lane = tid & 63, wid = tid >> 6;

    // hoisted per-chunk A-row metadata
    int tokq[2];
#pragma unroll
    for (int q = 0; q < 2; ++q) {
        int c = tid + (q << 8);
        if (MODE == 0) tokq[q] = gt[(c >> 3) * 256 + t];
    }

    f32x4 acc[4][4] = {};

    for (int k0 = 0; k0 < K; k0 += 64) {
        // ---- stage A: 512 chunks of 16B ----
#pragma unroll
        for (int q = 0; q < 2; ++q) {
            int c = tid + (q << 8);
            int row = c >> 3, kc = c & 7;
            int kcs = kc ^ (row & 7);  // swizzle on SOURCE; dest linear
            const u16* src;
            if (MODE == 0) {
                src = Asrc + (size_t)tokq[q] * 512 + k0 + (kcs << 3);
            } else {
                src = Asrc + ((size_t)t << 16) + ((size_t)((k0 >> 3) + kcs) << 9) + (row << 3);
            }
            gload16(src, Al + (q << 12) + (wid << 10));
        }
        // ---- stage B: 2048 chunks ----
#pragma unroll
        for (int q = 0; q < 8; ++q) {
            int c = tid + (q << 8);
            int row = c >> 3, kc = c & 7;
            int kcs = kc ^ (row & 7);
            gload16(Bmat + (size_t)(n0 + row) * K + k0 + (kcs << 3), Bl + (q << 12) + (wid << 10));
        }
        asm volatile("s_waitcnt vmcnt(0)" ::: "memory");
        __syncthreads();
#pragma unroll
        for (int kb2 = 0; kb2 < 2; ++kb2) {
            bf16x8 af[4], bf[4];
#pragma unroll
            for (int mt = 0; mt < 4; ++mt) {
                int row = (mt << 4) + (lane & 15);
                int kc = (kb2 << 2) + (lane >> 4);
                af[mt] = *(const bf16x8*)(Al + row * 128 + ((kc ^ (row & 7)) << 4));
            }
#pragma unroll
            for (int nt = 0; nt < 4; ++nt) {
                int row = (wid << 6) + (nt << 4) + (lane & 15);
                int kc = (kb2 << 2) + (lane >> 4);
                bf[nt] = *(const bf16x8*)(Bl + row * 128 + ((kc ^ (row & 7)) << 4));
            }
#pragma unroll
            for (int mt = 0; mt < 4; ++mt)
#pragma unroll
                for (int nt = 0; nt < 4; ++nt)
                    acc[mt][nt] = __builtin_amdgcn_mfma_f32_16x16x32_bf16(af[mt], bf[nt], acc[mt][nt], 0, 0, 0);
        }
        __syncthreads();
    }

#pragma unroll
    for (int nt = 0; nt < 4; ++nt) {
        int n = n0 + (wid << 6) + (nt << 4) + (lane & 15);
        float bv = 0.f;
        if (MODE == 0) bv = bias[n];
        else if (n < 8000) bv = bias[n];
#pragma unroll
        for (int mt = 0; mt < 4; ++mt) {
#pragma unroll
            for (int r = 0; r < 4; ++r) {
                int ml = (mt << 4) + ((lane >> 4) << 2) + r;
                float v = acc[mt][nt][r] + bv;
                if (MODE == 0) {
                    ((u16*)outp)[((size_t)((t << 6) + ml) << 12) + ((n & 1023) << 2) + (n >> 10)] = f2bf(v);
                } else {
                    // bf16 logits into the row's OWN f32 slot (stride 16000 u16)
                    if (n < 8000) ((u16*)outp)[(size_t)(ml * 255 + t) * 16000 + n] = f2bf(v);
                }
            }
        }
    }
}

// ---------------- persistent dataflow 2-layer LSTM (flag-based, split L2 loop) ----
// blocks 0..63:  layer1, j0=bid*16.  blocks 64..191: layer2, j0=(bid-64)*8.
// Publish: sc1 data stores -> vmcnt(0) -> __syncthreads -> ONE flag store/block.
// L2 loop split: {poll flg1[s+1] -> h1 read + Wih2-half MFMA} BEFORE the serial
// {poll flg2[s] -> h2 read + Whh2-half MFMA -> act -> publish}. H2 mirror store
// issues AFTER the flag (off the critical path; consumed only post-kernel).
__global__ __launch_bounds__(256, 1) void lstm_kernel(const u16* __restrict__ X1, const float* __restrict__ c0,
                                                      u16* __restrict__ h1ring, u16* __restrict__ h2ring,
                                                      u16* __restrict__ H2, const u16* __restrict__ Whh1,
                                                      const u16* __restrict__ Wih2, const u16* __restrict__ Whh2,
                                                      const float* __restrict__ b2, u32* __restrict__ flg1,
                                                      u32* __restrict__ flg2) {
    __shared__ uint4 WldsV[8192];  // 128 KiB weight slice
    __shared__ u64 scr[256];       // repack scratch (wave-private regions)
    char* Wb = (char*)WldsV;
    u16* scr16 = (u16*)scr;
    const int tid = threadIdx.x;
    const int lane = tid & 63, wid = tid >> 6;
    const int bid = blockIdx.x;
    const bool isL1 = (bid < 64);
    const int j0 = isL1 ? (bid << 4) : ((bid - 64) << 3);

    // ---- stage weights into LDS (XOR-swizzled rows) ----
    if (isL1) {
#pragma unroll 8
        for (int q = 0; q < 32; ++q) {
            int c = tid + (q << 8);
            int row = c >> 7, kc = c & 127;
            int gcol = ((row >> 4) << 10) + j0 + (row & 15);
            uint4 v = *(const uint4*)(Whh1 + ((size_t)gcol << 10) + (kc << 3));
            *(uint4*)(Wb + row * 2048 + ((kc ^ (row & 7)) << 4)) = v;
        }
    } else {
#pragma unroll 8
        for (int q = 0; q < 32; ++q) {
            int c = tid + (q << 8);
            int row = c >> 8, kc = c & 255;
            int gcol = ((row >> 3) << 10) + j0 + (row & 7);
            const u16* src = (kc < 128) ? (Wih2 + ((size_t)gcol << 10) + (kc << 3))
                                        : (Whh2 + ((size_t)gcol << 10) + ((kc - 128) << 3));
            uint4 v = *(const uint4*)src;
            *(uint4*)(Wb + row * 4096 + ((kc ^ (row & 7)) << 4)) = v;
        }
    }
    __syncthreads();

    const int arow = (wid << 4) + (lane & 15);
    const int jj16 = lane & 15;
    const int qhi = lane >> 5, qlo = (lane >> 4) & 1;

    if (isL1) {
        float creg[4];
#pragma unroll
        for (int r = 0; r < 4; ++r) {
            int b = (wid << 4) + ((lane >> 4) << 2) + r;
            creg[r] = c0[(b << 10) + j0 + jj16];
        }
        for (int i = 0; i < 255; ++i) {
            // X1 prefetch (issues before the poll; independent of h readiness)
            u64 xq[4];
#pragma unroll
            for (int r = 0; r < 4; ++r) {
                int b = (wid << 4) + ((lane >> 4) << 2) + r;
                xq[r] = *(const u64*)(X1 + ((size_t)((i << 6) + b) << 12) + ((j0 + jj16) << 2));
            }
            if (wid == 0) {
                long long g = 0;
                for (;;) {
                    u32 f = __hip_atomic_load(flg1 + (i << 6) + lane, __ATOMIC_RELAXED, __HIP_MEMORY_SCOPE_AGENT);
                    if (__all(f == 1u)) break;
                    __builtin_amdgcn_s_sleep(1);
                    if (++g > (1LL << 22)) break;  // safety net
                }
                asm volatile("" ::: "memory");
            }
            __syncthreads();
            const u16* abase = h1ring + ((size_t)i << 16) + ((size_t)qhi << 10) + ((size_t)arow << 4) + (qlo << 3);
            bf16x8 av[32];
#pragma unroll
            for (int kb = 0; kb < 32; ++kb) av[kb] = *(const bf16x8*)(abase + ((size_t)kb << 11));
            f32x4 acc[4] = {};
#pragma unroll
            for (int kb = 0; kb < 32; ++kb) {
                int kc = (kb << 2) + (lane >> 4);
#pragma unroll
                for (int g = 0; g < 4; ++g) {
                    int row = (g << 4) + jj16;
                    bf16x8 w = *(const bf16x8*)(Wb + row * 2048 + ((kc ^ (row & 7)) << 4));
                    acc[g] = __builtin_amdgcn_mfma_f32_16x16x32_bf16(av[kb], w, acc[g], 0, 0, 0);
                }
            }
#pragma unroll
            for (int r = 0; r < 4; ++r) {
                int b = (wid << 4) + ((lane >> 4) << 2) + r;
                float gi = acc[0][r] + bf2f((u16)(xq[r]));
                float gf = acc[1][r] + bf2f((u16)(xq[r] >> 16));
                float gg = acc[2][r] + bf2f((u16)(xq[r] >> 32));
                float go = acc[3][r] + bf2f((u16)(xq[r] >> 48));
                float cc = sigm(gf) * creg[r] + sigm(gi) * tanha(gg);
                creg[r] = cc;
                scr16[(b << 4) + jj16] = f2bf(sigm(go) * tanha(cc));
            }
            asm volatile("s_waitcnt lgkmcnt(0)" ::: "memory");
            // publish block-contiguous region: [slot i+1][jb=bid][b][jc]
            {
                u64 v = scr[(wid << 6) + lane];
                u16* dst = h1ring + ((size_t)(i + 1) << 16) + ((size_t)bid << 10) + (wid << 8) + (lane << 2);
                __hip_atomic_store((u64*)dst, v, __ATOMIC_RELAXED, __HIP_MEMORY_SCOPE_AGENT);
            }
            asm volatile("s_waitcnt vmcnt(0)" ::: "memory");
            __syncthreads();
            if (tid == 0)
                __hip_atomic_store(flg1 + ((i + 1) << 6) + bid, 1u, __ATOMIC_RELAXED, __HIP_MEMORY_SCOPE_AGENT);
        }
    } else {
        const int jb2 = bid - 64;
        float creg[4] = {0.f, 0.f, 0.f, 0.f};
        float b2v[4] = {0.f, 0.f, 0.f, 0.f};
        if ((lane & 15) < 8) {
            int jj = lane & 7;
#pragma unroll
            for (int g = 0; g < 4; ++g) b2v[g] = b2[(g << 10) + j0 + jj];
        }
        for (int s = 0; s < 255; ++s) {
            // ---- non-critical half: h1(s) is ready early (L1 runs ahead) ----
            if (wid == 0) {
                const u32* p1 = flg1 + ((s + 1) << 6) + lane;
                long long g = 0;
                for (;;) {
                    u32 a = __hip_atomic_load(p1, __ATOMIC_RELAXED, __HIP_MEMORY_SCOPE_AGENT);
                    if (__all(a == 1u)) break;
                    __builtin_amdgcn_s_sleep(1);
                    if (++g > (1LL << 22)) break;  // safety net
                }
                asm volatile("" ::: "memory");
            }
            __syncthreads();
            f32x4 acc[2] = {};
            {
                const u16* ab1 = h1ring + ((size_t)(s + 1) << 16) + ((size_t)qhi << 10) + ((size_t)arow << 4) + (qlo << 3);
                bf16x8 av[32];
#pragma unroll
                for (int kb = 0; kb < 32; ++kb) av[kb] = *(const bf16x8*)(ab1 + ((size_t)kb << 11));
#pragma unroll
                for (int kb = 0; kb < 32; ++kb) {
                    int kc = (kb << 2) + (lane >> 4);
#pragma unroll
                    for (int nt = 0; nt < 2; ++nt) {
                        int row = (nt << 4) + jj16;
                        bf16x8 w = *(const bf16x8*)(Wb + row * 4096 + ((kc ^ (row & 7)) << 4));
                        acc[nt] = __builtin_amdgcn_mfma_f32_16x16x32_bf16(av[kb], w, acc[nt], 0, 0, 0);
                    }
                }
            }
            // ---- serial half: wait h2(s-1), K-half 2 ----
            if (wid == 0) {
                const u64* p2 = (const u64*)(flg2 + (s << 7)) + lane;
                long long g = 0;
                for (;;) {
                    u64 b = __hip_atomic_load(p2, __ATOMIC_RELAXED, __HIP_MEMORY_SCOPE_AGENT);
                    if (__all(b == 0x0000000100000001ULL)) break;
                    __builtin_amdgcn_s_sleep(1);
                    if (++g > (1LL << 22)) break;  // safety net
                }
                asm volatile("" ::: "memory");
            }
            __syncthreads();
            {
                const u16* ab2 = h2ring + ((size_t)s << 16) + ((size_t)(lane >> 4) << 9) + ((size_t)arow << 3);
                bf16x8 bv[32];
#pragma unroll
                for (int kb = 0; kb < 32; ++kb) bv[kb] = *(const bf16x8*)(ab2 + ((size_t)kb << 11));
#pragma unroll
                for (int kb = 0; kb < 32; ++kb) {
                    int kc = ((kb + 32) << 2) + (lane >> 4);
#pragma unroll
                    for (int nt = 0; nt < 2; ++nt) {
                        int row = (nt << 4) + jj16;
                        bf16x8 w = *(const bf16x8*)(Wb + row * 4096 + ((kc ^ (row & 7)) << 4));
                        acc[nt] = __builtin_amdgcn_mfma_f32_16x16x32_bf16(bv[kb], w, acc[nt], 0, 0, 0);
                    }
                }
            }
            // gates: lane jj<8 holds {i,g}; partner jj+8 holds {f,o}
#pragma unroll
            for (int r = 0; r < 4; ++r) {
                float v0 = acc[0][r], v1 = acc[1][r];
                float p0 = __shfl_xor(v0, 8, 64);
                float p1 = __shfl_xor(v1, 8, 64);
                if ((lane & 15) < 8) {
                    int jj = lane & 7;
                    int b = (wid << 4) + ((lane >> 4) << 2) + r;
                    float gi = v0 + b2v[0];
                    float gf = p0 + b2v[1];
                    float gg = v1 + b2v[2];
                    float go = p1 + b2v[3];
                    float cc = sigm(gf) * creg[r] + sigm(gi) * tanha(gg);
                    creg[r] = cc;
                    scr16[(b << 3) + jj] = f2bf(sigm(go) * tanha(cc));
                }
            }
            asm volatile("s_waitcnt lgkmcnt(0)" ::: "memory");
            u64 v = 0;
            if (lane < 32) {
                v = scr[(wid << 5) + lane];
                // ring publish: [slot s+1][jb2][b][jc]
                u16* dst = h2ring + ((size_t)(s + 1) << 16) + ((size_t)jb2 << 9) + (wid << 7) + (lane << 2);
                __hip_atomic_store((u64*)dst, v, __ATOMIC_RELAXED, __HIP_MEMORY_SCOPE_AGENT);
            }
            asm volatile("s_waitcnt vmcnt(0)" ::: "memory");
            __syncthreads();
            if (tid == 0)
                __hip_atomic_store(flg2 + ((s + 1) << 7) + jb2, 1u, __ATOMIC_RELAXED, __HIP_MEMORY_SCOPE_AGENT);
            // H2 mirror AFTER the flag: off the critical path (consumed post-kernel)
            if (lane < 32)
                *(u64*)(H2 + ((size_t)s << 16) + ((size_t)jb2 << 9) + (wid << 7) + (lane << 2)) = v;
        }
    }
}

// ---------------- per-row log-softmax: bf16 logits (own slot) -> f32 output -------
__global__ __launch_bounds__(256) void lsm_kernel(float* __restrict__ out) {
    const u16* pi = (const u16*)out + (size_t)blockIdx.x * 16000;  // bf16 in own slot
    float* po = out + (size_t)blockIdx.x * 8000;
    const int tid = threadIdx.x;
    float4 v[8];
    float mx = -3.0e38f;
#pragma unroll
    for (int q = 0; q < 8; ++q) {
        int vi = tid + (q << 8);
        if (vi < 2000) {
            u64 w = *(const u64*)(pi + ((size_t)vi << 2));
            v[q].x = bf2f((u16)w);
            v[q].y = bf2f((u16)(w >> 16));
            v[q].z = bf2f((u16)(w >> 32));
            v[q].w = bf2f((u16)(w >> 48));
            mx = fmaxf(mx, fmaxf(fmaxf(v[q].x, v[q].y), fmaxf(v[q].z, v[q].w)));
        }
    }
#pragma unroll
    for (int o = 32; o >= 1; o >>= 1) mx = fmaxf(mx, __shfl_xor(mx, o, 64));
    __shared__ float red[8];
    if ((tid & 63) == 0) red[tid >> 6] = mx;
    __syncthreads();
    mx = fmaxf(fmaxf(red[0], red[1]), fmaxf(red[2], red[3]));
    float s = 0.f;
#pragma unroll
    for (int q = 0; q < 8; ++q) {
        int vi = tid + (q << 8);
        if (vi < 2000)
            s += __expf(v[q].x - mx) + __expf(v[q].y - mx) + __expf(v[q].z - mx) + __expf(v[q].w - mx);
    }
#pragma unroll
    for (int o = 32; o >= 1; o >>= 1) s += __shfl_xor(s, o, 64);
    if ((tid & 63) == 0) red[4 + (tid >> 6)] = s;
    __syncthreads();
    float lz = mx + logf(red[4] + red[5] + red[6] + red[7]);
#pragma unroll
    for (int q = 0; q < 8; ++q) {
        int vi = tid + (q << 8);
        if (vi < 2000) {
            float4 o4;
            o4.x = v[q].x - lz; o4.y = v[q].y - lz; o4.z = v[q].z - lz; o4.w = v[q].w - lz;
            *((float4*)po + vi) = o4;
        }
    }
}

// ---------------- host launch ----------------
extern "C" void kernel_launch(void* const* d_in, const int* in_sizes, int n_in,
                              void* d_out, int out_size, void* d_ws, size_t ws_size,
                              hipStream_t stream) {
    const int* gt = (const int*)d_in[0];
    const float* h0 = (const float*)d_in[1];
    const float* c0 = (const float*)d_in[2];
    const float* emb = (const float*)d_in[3];
    const float* Wih1 = (const float*)d_in[4];
    const float* Whh1 = (const float*)d_in[5];
    const float* bih1 = (const float*)d_in[6];
    const float* bhh1 = (const float*)d_in[7];
    const float* Wih2 = (const float*)d_in[8];
    const float* Whh2 = (const float*)d_in[9];
    const float* bih2 = (const float*)d_in[10];
    const float* bhh2 = (const float*)d_in[11];
    const float* Wout = (const float*)d_in[12];
    const float* bout = (const float*)d_in[13];

    char* w = (char*)d_ws;
    size_t off = 0;
    auto alloc = [&](size_t bytes) -> void* {
        void* p = (void*)(w + off);
        off = (off + bytes + 255) & ~(size_t)255;
        return p;
    };
    u32* flg1 = (u32*)alloc(16384 * 4);
    u32* flg2 = (u32*)alloc(32768 * 4);
    float* b1 = (float*)alloc(4096 * 4);
    float* b2 = (float*)alloc(4096 * 4);
    u16* embB = (u16*)alloc((size_t)8000 * 512 * 2);
    u16* Wih1B = (u16*)alloc((size_t)4096 * 512 * 2);
    u16* Whh1B = (u16*)alloc((size_t)4096 * 1024 * 2);
    u16* Wih2B = (u16*)alloc((size_t)4096 * 1024 * 2);
    u16* Whh2B = (u16*)alloc((size_t)4096 * 1024 * 2);
    u16* WoutB = (u16*)alloc((size_t)8192 * 1024 * 2);
    u16* H2 = (u16*)alloc((size_t)255 * 65536 * 2);

    // d_out (522.24 MB) scratch map: X1 at 0 (134 MB), rings at 136/168 MB — all
    // dead before phase C writes bf16 logits into each output row's own slot.
    u16* X1 = (u16*)d_out;
    u16* h1ring = (u16*)((char*)d_out + (size_t)136 * 1024 * 1024);
    u16* h2ring = (u16*)((char*)d_out + (size_t)168 * 1024 * 1024);

    // fused setup: all f32->bf16 converts + bias adds + ring/flag init (1 launch)
    {
        long long total = SOE;
        unsigned blocks = (unsigned)((total + 255) / 256);
        setup_kernel<<<blocks, 256, 0, stream>>>(emb, Wih1, Whh1, Wih2, Whh2, Wout,
                                                 bih1, bhh1, bih2, bhh2, h0,
                                                 embB, Wih1B, Whh1B, Wih2B, Whh2B, WoutB,
                                                 b1, b2, h1ring, h2ring, flg1, flg2);
    }

    // phase A: X1 = emb[gt] @ Wih1^T + b1  (bf16 gate-innermost, into d_out scratch)
    gemm_kernel<0, 512><<<dim3(16, 255), 256, 0, stream>>>(embB, Wih1B, gt, b1, (void*)X1);

    // phase B: persistent dataflow recurrence
    {
        void* args[] = {(void*)&X1, (void*)&c0, (void*)&h1ring, (void*)&h2ring, (void*)&H2,
                        (void*)&Whh1B, (void*)&Wih2B, (void*)&Whh2B, (void*)&b2,
                        (void*)&flg1, (void*)&flg2};
        (void)hipLaunchCooperativeKernel(reinterpret_cast<const void*>(&lstm_kernel),
                                         dim3(192), dim3(256), args, 0, stream);
    }

    // phase C: bf16 logits = H2 @ Wout^T + bout  (into each f32 row's own slot)
    gemm_kernel<1, 1024><<<dim3(32, 255), 256, 0, stream>>>(H2, WoutB, nullptr, bout, d_out);

    // log-softmax: bf16 (own slot) -> f32 output, per row
    lsm_kernel<<<16320, 256, 0, stream>>>((float*)d_out);
}

// Round 17
// 2508.968 us; speedup vs baseline: 1.0839x; 1.0009x over previous
//
#include <hip/hip_runtime.h>

typedef unsigned short u16;
typedef unsigned int u32;
typedef unsigned long long u64;
typedef __attribute__((ext_vector_type(8))) short bf16x8;
typedef __attribute__((ext_vector_type(4))) float f32x4;

#define DEV __device__ __forceinline__

DEV float bf2f(u16 u) { unsigned v = ((unsigned)u) << 16; float f; __builtin_memcpy(&f, &v, 4); return f; }
DEV u16 f2bf(float f) { unsigned u; __builtin_memcpy(&u, &f, 4); u += 0x7FFFu + ((u >> 16) & 1u); return (u16)(u >> 16); }
DEV float sigm(float x) { return 1.f / (1.f + __expf(-x)); }
DEV float tanha(float x) { x = fminf(9.f, fmaxf(-9.f, x)); float t = __expf(2.f * x); return (t - 1.f) / (t + 1.f); }

// async global->LDS, 16B per lane; LDS dest is wave-uniform base + lane*16 (linear).
// XOR-swizzle pre-applied to the GLOBAL source address (involution; m104/m173 rule).
DEV void gload16(const void* g, void* l) {
    __builtin_amdgcn_global_load_lds((const __attribute__((address_space(1))) unsigned*)g,
                                     (__attribute__((address_space(3))) unsigned*)l, 16, 0, 0);
}

// bf16 logits live INSIDE each f32 output row's own slot: row r's bf16 data at byte
// 32000*r (stride 16000 u16, first 8000 used). Each lsm block reads only its own
// slot and writes only its own slot -> zero cross-block aliasing; self-overlap safe:
// all loads are consumed into registers (forced by the max reduction before the
// first __syncthreads) before any store.

// ---------------- fused setup: all converts + bias adds + ring/flag init ----------
#define SO0 0LL
#define SO1 (SO0 + 1024000LL)
#define SO2 (SO1 + 524288LL)
#define SO3 (SO2 + 1048576LL)
#define SO4 (SO3 + 1048576LL)
#define SO5 (SO4 + 1048576LL)
#define SO6 (SO5 + 2097152LL)
#define SO7 (SO6 + 2048LL)
#define SO8 (SO7 + 16384LL)
#define SO9 (SO8 + 4096LL)
#define SOE (SO9 + 8192LL)

DEV void cvt4(const float* __restrict__ s, u16* __restrict__ d, long long i) {
    float4 v = *(const float4*)(s + i);
    uint2 o;
    o.x = (unsigned)f2bf(v.x) | ((unsigned)f2bf(v.y) << 16);
    o.y = (unsigned)f2bf(v.z) | ((unsigned)f2bf(v.w) << 16);
    *(uint2*)(d + i) = o;
}

__global__ __launch_bounds__(256) void setup_kernel(
    const float* __restrict__ emb, const float* __restrict__ Wih1, const float* __restrict__ Whh1,
    const float* __restrict__ Wih2, const float* __restrict__ Whh2, const float* __restrict__ Wout,
    const float* __restrict__ bih1, const float* __restrict__ bhh1, const float* __restrict__ bih2,
    const float* __restrict__ bhh2, const float* __restrict__ h0,
    u16* __restrict__ embB, u16* __restrict__ Wih1B, u16* __restrict__ Whh1B, u16* __restrict__ Wih2B,
    u16* __restrict__ Whh2B, u16* __restrict__ WoutB, float* __restrict__ b1, float* __restrict__ b2,
    u16* __restrict__ h1ring, u16* __restrict__ h2ring, u32* __restrict__ flg1, u32* __restrict__ flg2) {
    long long q = (long long)blockIdx.x * 256 + threadIdx.x;
    if (q < SO1) {
        cvt4(emb, embB, (q - SO0) << 2);
    } else if (q < SO2) {
        cvt4(Wih1, Wih1B, (q - SO1) << 2);
    } else if (q < SO3) {
        cvt4(Whh1, Whh1B, (q - SO2) << 2);
    } else if (q < SO4) {
        cvt4(Wih2, Wih2B, (q - SO3) << 2);
    } else if (q < SO5) {
        cvt4(Whh2, Whh2B, (q - SO4) << 2);
    } else if (q < SO6) {
        long long i = (q - SO5) << 2;
        int row = (int)(i >> 10), col = (int)(i & 1023);
        uint2 o;
        if (row < 8000) {
            float4 v = *(const float4*)(Wout + (size_t)row * 1024 + col);
            o.x = (unsigned)f2bf(v.x) | ((unsigned)f2bf(v.y) << 16);
            o.y = (unsigned)f2bf(v.z) | ((unsigned)f2bf(v.w) << 16);
        } else { o.x = 0u; o.y = 0u; }
        *(uint2*)(WoutB + i) = o;
    } else if (q < SO7) {
        int i = (int)(q - SO6) << 2;
        if (i < 4096) {
            float4 a = *(const float4*)(bih1 + i), b = *(const float4*)(bhh1 + i);
            float4 o; o.x = a.x + b.x; o.y = a.y + b.y; o.z = a.z + b.z; o.w = a.w + b.w;
            *(float4*)(b1 + i) = o;
        } else {
            int j = i - 4096;
            float4 a = *(const float4*)(bih2 + j), b = *(const float4*)(bhh2 + j);
            float4 o; o.x = a.x + b.x; o.y = a.y + b.y; o.z = a.z + b.z; o.w = a.w + b.w;
            *(float4*)(b2 + j) = o;
        }
    } else if (q < SO8) {
        int i = (int)(q - SO7) << 2;  // 4 consecutive cols, same b
        int b = i >> 10, col = i & 1023;
        float4 v = *(const float4*)(h0 + i);
        u64 hv = (u64)f2bf(v.x) | ((u64)f2bf(v.y) << 16) | ((u64)f2bf(v.z) << 32) | ((u64)f2bf(v.w) << 48);
        *(u64*)(h1ring + ((col >> 4) << 10) + (b << 4) + (col & 15)) = hv;  // slot0 = h0
        *(u64*)(h2ring + i) = 0;                                           // slot0 = 0
    } else if (q < SO9) {
        int i = (int)(q - SO8) << 2;
        uint4 o;
        o.x = (i < 64) ? 1u : 0u; o.y = (i + 1 < 64) ? 1u : 0u;
        o.z = (i + 2 < 64) ? 1u : 0u; o.w = (i + 3 < 64) ? 1u : 0u;
        *(uint4*)(flg1 + i) = o;
    } else if (q < SOE) {
        int i = (int)(q - SO9) << 2;
        uint4 o;
        o.x = (i < 128) ? 1u : 0u; o.y = (i + 1 < 128) ? 1u : 0u;
        o.z = (i + 2 < 128) ? 1u : 0u; o.w = (i + 3 < 128) ? 1u : 0u;
        *(uint4*)(flg2 + i) = o;
    }
}

// ---------------- generic 64x256-tile bf16 GEMM (C = A @ B^T + bias) ----------------
// MODE 0: phase A, K=512, A-row = emb[gt]; out X1 gate-innermost: X1[(t*64+m)*4096 + j*4 + g].
// MODE 1: phase C, K=1024, A-row = H2 [t][k>>3][row][k&7]; out BF16 logits into d_out
//         at row slot stride 16000 u16 (row = b*255+t, first 8000 u16 used).
template <int MODE, int K>
__global__ __launch_bounds__(256) void gemm_kernel(const u16* __restrict__ Asrc, const u16* __restrict__ Bmat,
                                                   const int* __restrict__ gt, const float* __restrict__ bias,
                                                   void* __restrict__ outp) {
    __shared__ uint4 AldsV[512];   // 64 x 64 bf16 = 8 KiB
    __shared__ uint4 BldsV[2048];  // 256 x 64 bf16 = 32 KiB
    char* Al = (char*)AldsV;
    char* Bl = (char*)BldsV;
    const int t = blockIdx.y;
    const int n0 = blockIdx.x << 8;
    const int tid = threadIdx.x;
    const int lane = tid & 63, wid = tid >> 6;

    int tokq[2];
#pragma unroll
    for (int q = 0; q < 2; ++q) {
        int c = tid + (q << 8);
        if (MODE == 0) tokq[q] = gt[(c >> 3) * 256 + t];
    }

    f32x4 acc[4][4] = {};

    for (int k0 = 0; k0 < K; k0 += 64) {
#pragma unroll
        for (int q = 0; q < 2; ++q) {
            int c = tid + (q << 8);
            int row = c >> 3, kc = c & 7;
            int kcs = kc ^ (row & 7);  // swizzle on SOURCE; dest linear
            const u16* src;
            if (MODE == 0) {
                src = Asrc + (size_t)tokq[q] * 512 + k0 + (kcs << 3);
            } else {
                src = Asrc + ((size_t)t << 16) + ((size_t)((k0 >> 3) + kcs) << 9) + (row << 3);
            }
            gload16(src, Al + (q << 12) + (wid << 10));
        }
#pragma unroll
        for (int q = 0; q < 8; ++q) {
            int c = tid + (q << 8);
            int row = c >> 3, kc = c & 7;
            int kcs = kc ^ (row & 7);
            gload16(Bmat + (size_t)(n0 + row) * K + k0 + (kcs << 3), Bl + (q << 12) + (wid << 10));
        }
        asm volatile("s_waitcnt vmcnt(0)" ::: "memory");
        __syncthreads();
#pragma unroll
        for (int kb2 = 0; kb2 < 2; ++kb2) {
            bf16x8 af[4], bf[4];
#pragma unroll
            for (int mt = 0; mt < 4; ++mt) {
                int row = (mt << 4) + (lane & 15);
                int kc = (kb2 << 2) + (lane >> 4);
                af[mt] = *(const bf16x8*)(Al + row * 128 + ((kc ^ (row & 7)) << 4));
            }
#pragma unroll
            for (int nt = 0; nt < 4; ++nt) {
                int row = (wid << 6) + (nt << 4) + (lane & 15);
                int kc = (kb2 << 2) + (lane >> 4);
                bf[nt] = *(const bf16x8*)(Bl + row * 128 + ((kc ^ (row & 7)) << 4));
            }
#pragma unroll
            for (int mt = 0; mt < 4; ++mt)
#pragma unroll
                for (int nt = 0; nt < 4; ++nt)
                    acc[mt][nt] = __builtin_amdgcn_mfma_f32_16x16x32_bf16(af[mt], bf[nt], acc[mt][nt], 0, 0, 0);
        }
        __syncthreads();
    }

#pragma unroll
    for (int nt = 0; nt < 4; ++nt) {
        int n = n0 + (wid << 6) + (nt << 4) + (lane & 15);
        float bv = 0.f;
        if (MODE == 0) bv = bias[n];
        else if (n < 8000) bv = bias[n];
#pragma unroll
        for (int mt = 0; mt < 4; ++mt) {
#pragma unroll
            for (int r = 0; r < 4; ++r) {
                int ml = (mt << 4) + ((lane >> 4) << 2) + r;
                float v = acc[mt][nt][r] + bv;
                if (MODE == 0) {
                    ((u16*)outp)[((size_t)((t << 6) + ml) << 12) + ((n & 1023) << 2) + (n >> 10)] = f2bf(v);
                } else {
                    if (n < 8000) ((u16*)outp)[(size_t)(ml * 255 + t) * 16000 + n] = f2bf(v);
                }
            }
        }
    }
}

// ---------------- persistent dataflow 2-layer LSTM (flag-based, split L2 loop) ----
// blocks 0..63:  layer1, j0=bid*16.  blocks 64..191: layer2, j0=(bid-64)*8.
// Publish: sc1 data stores -> vmcnt(0) -> __syncthreads -> ONE flag store/block.
// L2 loop split: {poll flg1[s+1] -> h1 read + Wih2-half MFMA} BEFORE the serial
// {poll flg2[s] -> h2 read + Whh2-half MFMA -> act -> publish}. H2 mirror store
// issues AFTER the flag (off the critical path; consumed only post-kernel).
__global__ __launch_bounds__(256, 1) void lstm_kernel(const u16* __restrict__ X1, const float* __restrict__ c0,
                                                      u16* __restrict__ h1ring, u16* __restrict__ h2ring,
                                                      u16* __restrict__ H2, const u16* __restrict__ Whh1,
                                                      const u16* __restrict__ Wih2, const u16* __restrict__ Whh2,
                                                      const float* __restrict__ b2, u32* __restrict__ flg1,
                                                      u32* __restrict__ flg2) {
    __shared__ uint4 WldsV[8192];  // 128 KiB weight slice
    __shared__ u64 scr[256];       // repack scratch (wave-private regions)
    char* Wb = (char*)WldsV;
    u16* scr16 = (u16*)scr;
    const int tid = threadIdx.x;
    const int lane = tid & 63, wid = tid >> 6;
    const int bid = blockIdx.x;
    const bool isL1 = (bid < 64);
    const int j0 = isL1 ? (bid << 4) : ((bid - 64) << 3);

    if (isL1) {
#pragma unroll 8
        for (int q = 0; q < 32; ++q) {
            int c = tid + (q << 8);
            int row = c >> 7, kc = c & 127;
            int gcol = ((row >> 4) << 10) + j0 + (row & 15);
            uint4 v = *(const uint4*)(Whh1 + ((size_t)gcol << 10) + (kc << 3));
            *(uint4*)(Wb + row * 2048 + ((kc ^ (row & 7)) << 4)) = v;
        }
    } else {
#pragma unroll 8
        for (int q = 0; q < 32; ++q) {
            int c = tid + (q << 8);
            int row = c >> 8, kc = c & 255;
            int gcol = ((row >> 3) << 10) + j0 + (row & 7);
            const u16* src = (kc < 128) ? (Wih2 + ((size_t)gcol << 10) + (kc << 3))
                                        : (Whh2 + ((size_t)gcol << 10) + ((kc - 128) << 3));
            uint4 v = *(const uint4*)src;
            *(uint4*)(Wb + row * 4096 + ((kc ^ (row & 7)) << 4)) = v;
        }
    }
    __syncthreads();

    const int arow = (wid << 4) + (lane & 15);
    const int jj16 = lane & 15;
    const int qhi = lane >> 5, qlo = (lane >> 4) & 1;

    if (isL1) {
        float creg[4];
#pragma unroll
        for (int r = 0; r < 4; ++r) {
            int b = (wid << 4) + ((lane >> 4) << 2) + r;
            creg[r] = c0[(b << 10) + j0 + jj16];
        }
        for (int i = 0; i < 255; ++i) {
            u64 xq[4];
#pragma unroll
            for (int r = 0; r < 4; ++r) {
                int b = (wid << 4) + ((lane >> 4) << 2) + r;
                xq[r] = *(const u64*)(X1 + ((size_t)((i << 6) + b) << 12) + ((j0 + jj16) << 2));
            }
            if (wid == 0) {
                long long g = 0;
                for (;;) {
                    u32 f = __hip_atomic_load(flg1 + (i << 6) + lane, __ATOMIC_RELAXED, __HIP_MEMORY_SCOPE_AGENT);
                    if (__all(f == 1u)) break;
                    __builtin_amdgcn_s_sleep(1);
                    if (++g > (1LL << 22)) break;  // safety net
                }
                asm volatile("" ::: "memory");
            }
            __syncthreads();
            const u16* abase = h1ring + ((size_t)i << 16) + ((size_t)qhi << 10) + ((size_t)arow << 4) + (qlo << 3);
            bf16x8 av[32];
#pragma unroll
            for (int kb = 0; kb < 32; ++kb) av[kb] = *(const bf16x8*)(abase + ((size_t)kb << 11));
            f32x4 acc[4] = {};
#pragma unroll
            for (int kb = 0; kb < 32; ++kb) {
                int kc = (kb << 2) + (lane >> 4);
#pragma unroll
                for (int g = 0; g < 4; ++g) {
                    int row = (g << 4) + jj16;
                    bf16x8 w = *(const bf16x8*)(Wb + row * 2048 + ((kc ^ (row & 7)) << 4));
                    acc[g] = __builtin_amdgcn_mfma_f32_16x16x32_bf16(av[kb], w, acc[g], 0, 0, 0);
                }
            }
#pragma unroll
            for (int r = 0; r < 4; ++r) {
                int b = (wid << 4) + ((lane >> 4) << 2) + r;
                float gi = acc[0][r] + bf2f((u16)(xq[r]));
                float gf = acc[1][r] + bf2f((u16)(xq[r] >> 16));
                float gg = acc[2][r] + bf2f((u16)(xq[r] >> 32));
                float go = acc[3][r] + bf2f((u16)(xq[r] >> 48));
                float cc = sigm(gf) * creg[r] + sigm(gi) * tanha(gg);
                creg[r] = cc;
                scr16[(b << 4) + jj16] = f2bf(sigm(go) * tanha(cc));
            }
            asm volatile("s_waitcnt lgkmcnt(0)" ::: "memory");
            {
                u64 v = scr[(wid << 6) + lane];
                u16* dst = h1ring + ((size_t)(i + 1) << 16) + ((size_t)bid << 10) + (wid << 8) + (lane << 2);
                __hip_atomic_store((u64*)dst, v, __ATOMIC_RELAXED, __HIP_MEMORY_SCOPE_AGENT);
            }
            asm volatile("s_waitcnt vmcnt(0)" ::: "memory");
            __syncthreads();
            if (tid == 0)
                __hip_atomic_store(flg1 + ((i + 1) << 6) + bid, 1u, __ATOMIC_RELAXED, __HIP_MEMORY_SCOPE_AGENT);
        }
    } else {
        const int jb2 = bid - 64;
        float creg[4] = {0.f, 0.f, 0.f, 0.f};
        float b2v[4] = {0.f, 0.f, 0.f, 0.f};
        if ((lane & 15) < 8) {
            int jj = lane & 7;
#pragma unroll
            for (int g = 0; g < 4; ++g) b2v[g] = b2[(g << 10) + j0 + jj];
        }
        for (int s = 0; s < 255; ++s) {
            if (wid == 0) {
                const u32* p1 = flg1 + ((s + 1) << 6) + lane;
                long long g = 0;
                for (;;) {
                    u32 a = __hip_atomic_load(p1, __ATOMIC_RELAXED, __HIP_MEMORY_SCOPE_AGENT);
                    if (__all(a == 1u)) break;
                    __builtin_amdgcn_s_sleep(1);
                    if (++g > (1LL << 22)) break;  // safety net
                }
                asm volatile("" ::: "memory");
            }
            __syncthreads();
            f32x4 acc[2] = {};
            {
                const u16* ab1 = h1ring + ((size_t)(s + 1) << 16) + ((size_t)qhi << 10) + ((size_t)arow << 4) + (qlo << 3);
                bf16x8 av[32];
#pragma unroll
                for (int kb = 0; kb < 32; ++kb) av[kb] = *(const bf16x8*)(ab1 + ((size_t)kb << 11));
#pragma unroll
                for (int kb = 0; kb < 32; ++kb) {
                    int kc = (kb << 2) + (lane >> 4);
#pragma unroll
                    for (int nt = 0; nt < 2; ++nt) {
                        int row = (nt << 4) + jj16;
                        bf16x8 w = *(const bf16x8*)(Wb + row * 4096 + ((kc ^ (row & 7)) << 4));
                        acc[nt] = __builtin_amdgcn_mfma_f32_16x16x32_bf16(av[kb], w, acc[nt], 0, 0, 0);
                    }
                }
            }
            if (wid == 0) {
                const u64* p2 = (const u64*)(flg2 + (s << 7)) + lane;
                long long g = 0;
                for (;;) {
                    u64 b = __hip_atomic_load(p2, __ATOMIC_RELAXED, __HIP_MEMORY_SCOPE_AGENT);
                    if (__all(b == 0x0000000100000001ULL)) break;
                    __builtin_amdgcn_s_sleep(1);
                    if (++g > (1LL << 22)) break;  // safety net
                }
                asm volatile("" ::: "memory");
            }
            __syncthreads();
            {
                const u16* ab2 = h2ring + ((size_t)s << 16) + ((size_t)(lane >> 4) << 9) + ((size_t)arow << 3);
                bf16x8 bv[32];
#pragma unroll
                for (int kb = 0; kb < 32; ++kb) bv[kb] = *(const bf16x8*)(ab2 + ((size_t)kb << 11));
#pragma unroll
                for (int kb = 0; kb < 32; ++kb) {
                    int kc = ((kb + 32) << 2) + (lane >> 4);
#pragma unroll
                    for (int nt = 0; nt < 2; ++nt) {
                        int row = (nt << 4) + jj16;
                        bf16x8 w = *(const bf16x8*)(Wb + row * 4096 + ((kc ^ (row & 7)) << 4));
                        acc[nt] = __builtin_amdgcn_mfma_f32_16x16x32_bf16(bv[kb], w, acc[nt], 0, 0, 0);
                    }
                }
            }
#pragma unroll
            for (int r = 0; r < 4; ++r) {
                float v0 = acc[0][r], v1 = acc[1][r];
                float p0 = __shfl_xor(v0, 8, 64);
                float p1 = __shfl_xor(v1, 8, 64);
                if ((lane & 15) < 8) {
                    int jj = lane & 7;
                    int b = (wid << 4) + ((lane >> 4) << 2) + r;
                    float gi = v0 + b2v[0];
                    float gf = p0 + b2v[1];
                    float gg = v1 + b2v[2];
                    float go = p1 + b2v[3];
                    float cc = sigm(gf) * creg[r] + sigm(gi) * tanha(gg);
                    creg[r] = cc;
                    scr16[(b << 3) + jj] = f2bf(sigm(go) * tanha(cc));
                }
            }
            asm volatile("s_waitcnt lgkmcnt(0)" ::: "memory");
            u64 v = 0;
            if (lane < 32) {
                v = scr[(wid << 5) + lane];
                u16* dst = h2ring + ((size_t)(s + 1) << 16) + ((size_t)jb2 << 9) + (wid << 7) + (lane << 2);
                __hip_atomic_store((u64*)dst, v, __ATOMIC_RELAXED, __HIP_MEMORY_SCOPE_AGENT);
            }
            asm volatile("s_waitcnt vmcnt(0)" ::: "memory");
            __syncthreads();
            if (tid == 0)
                __hip_atomic_store(flg2 + ((s + 1) << 7) + jb2, 1u, __ATOMIC_RELAXED, __HIP_MEMORY_SCOPE_AGENT);
            if (lane < 32)
                *(u64*)(H2 + ((size_t)s << 16) + ((size_t)jb2 << 9) + (wid << 7) + (lane << 2)) = v;
        }
    }
}

// ---------------- per-row log-softmax: bf16 logits (own slot) -> f32 output -------
__global__ __launch_bounds__(256) void lsm_kernel(float* __restrict__ out) {
    const u16* pi = (const u16*)out + (size_t)blockIdx.x * 16000;  // bf16 in own slot
    float* po = out + (size_t)blockIdx.x * 8000;
    const int tid = threadIdx.x;
    float4 v[8];
    float mx = -3.0e38f;
#pragma unroll
    for (int q = 0; q < 8; ++q) {
        int vi = tid + (q << 8);
        if (vi < 2000) {
            u64 w = *(const u64*)(pi + ((size_t)vi << 2));
            v[q].x = bf2f((u16)w);
            v[q].y = bf2f((u16)(w >> 16));
            v[q].z = bf2f((u16)(w >> 32));
            v[q].w = bf2f((u16)(w >> 48));
            mx = fmaxf(mx, fmaxf(fmaxf(v[q].x, v[q].y), fmaxf(v[q].z, v[q].w)));
        }
    }
#pragma unroll
    for (int o = 32; o >= 1; o >>= 1) mx = fmaxf(mx, __shfl_xor(mx, o, 64));
    __shared__ float red[8];
    if ((tid & 63) == 0) red[tid >> 6] = mx;
    __syncthreads();
    mx = fmaxf(fmaxf(red[0], red[1]), fmaxf(red[2], red[3]));
    float s = 0.f;
#pragma unroll
    for (int q = 0; q < 8; ++q) {
        int vi = tid + (q << 8);
        if (vi < 2000)
            s += __expf(v[q].x - mx) + __expf(v[q].y - mx) + __expf(v[q].z - mx) + __expf(v[q].w - mx);
    }
#pragma unroll
    for (int o = 32; o >= 1; o >>= 1) s += __shfl_xor(s, o, 64);
    if ((tid & 63) == 0) red[4 + (tid >> 6)] = s;
    __syncthreads();
    float lz = mx + logf(red[4] + red[5] + red[6] + red[7]);
#pragma unroll
    for (int q = 0; q < 8; ++q) {
        int vi = tid + (q << 8);
        if (vi < 2000) {
            float4 o4;
            o4.x = v[q].x - lz; o4.y = v[q].y - lz; o4.z = v[q].z - lz; o4.w = v[q].w - lz;
            *((float4*)po + vi) = o4;
        }
    }
}

// ---------------- host launch ----------------
extern "C" void kernel_launch(void* const* d_in, const int* in_sizes, int n_in,
                              void* d_out, int out_size, void* d_ws, size_t ws_size,
                              hipStream_t stream) {
    const int* gt = (const int*)d_in[0];
    const float* h0 = (const float*)d_in[1];
    const float* c0 = (const float*)d_in[2];
    const float* emb = (const float*)d_in[3];
    const float* Wih1 = (const float*)d_in[4];
    const float* Whh1 = (const float*)d_in[5];
    const float* bih1 = (const float*)d_in[6];
    const float* bhh1 = (const float*)d_in[7];
    const float* Wih2 = (const float*)d_in[8];
    const float* Whh2 = (const float*)d_in[9];
    const float* bih2 = (const float*)d_in[10];
    const float* bhh2 = (const float*)d_in[11];
    const float* Wout = (const float*)d_in[12];
    const float* bout = (const float*)d_in[13];

    char* w = (char*)d_ws;
    size_t off = 0;
    auto alloc = [&](size_t bytes) -> void* {
        void* p = (void*)(w + off);
        off = (off + bytes + 255) & ~(size_t)255;
        return p;
    };
    u32* flg1 = (u32*)alloc(16384 * 4);
    u32* flg2 = (u32*)alloc(32768 * 4);
    float* b1 = (float*)alloc(4096 * 4);
    float* b2 = (float*)alloc(4096 * 4);
    u16* embB = (u16*)alloc((size_t)8000 * 512 * 2);
    u16* Wih1B = (u16*)alloc((size_t)4096 * 512 * 2);
    u16* Whh1B = (u16*)alloc((size_t)4096 * 1024 * 2);
    u16* Wih2B = (u16*)alloc((size_t)4096 * 1024 * 2);
    u16* Whh2B = (u16*)alloc((size_t)4096 * 1024 * 2);
    u16* WoutB = (u16*)alloc((size_t)8192 * 1024 * 2);
    u16* H2 = (u16*)alloc((size_t)255 * 65536 * 2);

    // d_out (522.24 MB) scratch map: X1 at 0 (134 MB), rings at 136/168 MB — all
    // dead before phase C writes bf16 logits into each output row's own slot.
    u16* X1 = (u16*)d_out;
    u16* h1ring = (u16*)((char*)d_out + (size_t)136 * 1024 * 1024);
    u16* h2ring = (u16*)((char*)d_out + (size_t)168 * 1024 * 1024);

    // fused setup: all f32->bf16 converts + bias adds + ring/flag init (1 launch)
    {
        long long total = SOE;
        unsigned blocks = (unsigned)((total + 255) / 256);
        setup_kernel<<<blocks, 256, 0, stream>>>(emb, Wih1, Whh1, Wih2, Whh2, Wout,
                                                 bih1, bhh1, bih2, bhh2, h0,
                                                 embB, Wih1B, Whh1B, Wih2B, Whh2B, WoutB,
                                                 b1, b2, h1ring, h2ring, flg1, flg2);
    }

    // phase A: X1 = emb[gt] @ Wih1^T + b1  (bf16 gate-innermost, into d_out scratch)
    gemm_kernel<0, 512><<<dim3(16, 255), 256, 0, stream>>>(embB, Wih1B, gt, b1, (void*)X1);

    // phase B: persistent dataflow recurrence
    {
        void* args[] = {(void*)&X1, (void*)&c0, (void*)&h1ring, (void*)&h2ring, (void*)&H2,
                        (void*)&Whh1B, (void*)&Wih2B, (void*)&Whh2B, (void*)&b2,
                        (void*)&flg1, (void*)&flg2};
        (void)hipLaunchCooperativeKernel(reinterpret_cast<const void*>(&lstm_kernel),
                                         dim3(192), dim3(256), args, 0, stream);
    }

    // phase C: bf16 logits = H2 @ Wout^T + bout  (into each f32 row's own slot)
    gemm_kernel<1, 1024><<<dim3(32, 255), 256, 0, stream>>>(H2, WoutB, nullptr, bout, d_out);

    // log-softmax: bf16 (own slot) -> f32 output, per row
    lsm_kernel<<<16320, 256, 0, stream>>>((float*)d_out);
}